// Round 10
// baseline (495.196 us; speedup 1.0000x reference)
//
#include <hip/hip_runtime.h>
#include <hip/hip_bf16.h>

#define DEVFN __device__ __forceinline__
#define SB __builtin_amdgcn_sched_barrier(0)

typedef __attribute__((ext_vector_type(4))) float f32x4;
typedef __attribute__((ext_vector_type(8))) short s16x8;
typedef __attribute__((ext_vector_type(2))) short s16x2;
typedef __attribute__((ext_vector_type(8))) __bf16 bf16x8;

union FragU { s16x8 s; bf16x8 b; };

DEVFN short f2bs(float x) {
  union { __hip_bfloat16 h; short s; } u;
  u.h = __float2bfloat16(x);
  return u.s;
}

DEVFN void gload16(const void* g, void* l) {
  __builtin_amdgcn_global_load_lds(
      (const __attribute__((address_space(1))) void*)g,
      (__attribute__((address_space(3))) void*)l, 16, 0, 0);
}

template <int N> DEVFN void waitcnt_vm() {
  if constexpr (N == 0) asm volatile("s_waitcnt vmcnt(0)" ::: "memory");
  else if constexpr (N == 2) asm volatile("s_waitcnt vmcnt(2)" ::: "memory");
  else if constexpr (N == 3) asm volatile("s_waitcnt vmcnt(3)" ::: "memory");
  else if constexpr (N == 4) asm volatile("s_waitcnt vmcnt(4)" ::: "memory");
  else if constexpr (N == 6) asm volatile("s_waitcnt vmcnt(6)" ::: "memory");
  else if constexpr (N == 8) asm volatile("s_waitcnt vmcnt(8)" ::: "memory");
  else static_assert(N == 0, "unsupported vmcnt");
}

// in: [Z][C][L] f32 -> out: [Z][L][C] bf16.
__global__ __launch_bounds__(256) void transpose_cvt(
    const float* __restrict__ in, short* __restrict__ out, int C, int L) {
  __shared__ float tile[64][33];
  const int l0 = blockIdx.x * 32, c0 = blockIdx.y * 64;
  const size_t base = (size_t)blockIdx.z * C * L;
  const int tx = threadIdx.x, ty = threadIdx.y;
#pragma unroll
  for (int i = ty; i < 64; i += 8)
    tile[i][tx] = in[base + (size_t)(c0 + i) * L + l0 + tx];
  __syncthreads();
#pragma unroll
  for (int i = ty; i < 32; i += 8) {
    s16x2 v;
    v[0] = f2bs(tile[2 * tx][i]);
    v[1] = f2bs(tile[2 * tx + 1][i]);
    *(s16x2*)&out[base + (size_t)(l0 + i) * C + c0 + 2 * tx] = v;
  }
}

// All six weight transposes + both bias concats, one launch.
__global__ __launch_bounds__(256) void prep_weights(
    const float* __restrict__ Wq1, const float* __restrict__ Wk1,
    const float* __restrict__ Wv1, const float* __restrict__ Wq2,
    const float* __restrict__ Wk2, const float* __restrict__ Wv2,
    short* wq1t, short* wk1t, short* wv1t,
    short* wq2t, short* wk2t, short* wv2t,
    const float* __restrict__ bq1, const float* __restrict__ bk1,
    const float* __restrict__ bq2, const float* __restrict__ bk2,
    float* b1c, float* b2c) {
  const int z = blockIdx.z;
  if (z == 6) {
    if (blockIdx.y != 0 || blockIdx.x >= 8) return;
    const int bx = blockIdx.x;
    const int tid = threadIdx.y * 32 + threadIdx.x;
    const int i = (bx & 3) * 256 + tid;
    const float* s = (bx < 4) ? ((i < 512) ? bq1 : bk1)
                              : ((i < 512) ? bq2 : bk2);
    float* d = (bx < 4) ? b1c : b2c;
    d[i] = s[i & 511];
    return;
  }
  const float* W; short* O; int C;
  switch (z) {
    case 0: W = Wq1; O = wq1t; C = 512; break;
    case 1: W = Wk1; O = wk1t; C = 512; break;
    case 2: W = Wv1; O = wv1t; C = 512; break;
    case 3: W = Wq2; O = wq2t; C = 768; break;
    case 4: W = Wk2; O = wk2t; C = 768; break;
    default: W = Wv2; O = wv2t; C = 768; break;
  }
  if (blockIdx.y * 64 >= (unsigned)C) return;
  const int L = 512;
  __shared__ float tile[64][33];
  const int l0 = blockIdx.x * 32, c0 = blockIdx.y * 64;
  const int tx = threadIdx.x, ty = threadIdx.y;
#pragma unroll
  for (int i = ty; i < 64; i += 8)
    tile[i][tx] = W[(size_t)(c0 + i) * L + l0 + tx];
  __syncthreads();
#pragma unroll
  for (int i = ty; i < 32; i += 8) {
    s16x2 v;
    v[0] = f2bs(tile[2 * tx][i]);
    v[1] = f2bs(tile[2 * tx + 1][i]);
    *(s16x2*)&O[(size_t)(l0 + i) * C + c0 + 2 * tx] = v;
  }
}

// ---------------------------------------------------------------------------
// Dual-GEMM launch (R8, unchanged): deep-pipelined 256x256, used for P1/P2.
// ---------------------------------------------------------------------------
template <int OUTMODE, int BIASMODE, int MR>
__global__ __launch_bounds__(512, 2) void gemm8d(
    const short* __restrict__ A0, const short* __restrict__ B0,
    const float* __restrict__ bias0, void* __restrict__ C0, short* __restrict__ D0,
    int K0, int lda0, int ldb0, int ldc0,
    long long sA0, long long sB0, long long sC0,
    unsigned gx0, unsigned gy0, unsigned nb0,
    const short* __restrict__ A1, const short* __restrict__ B1,
    const float* __restrict__ bias1, void* __restrict__ C1, short* __restrict__ D1,
    int K1, int lda1, int ldb1, int ldc1,
    long long sA1, long long sB1, long long sC1,
    unsigned gx1, unsigned gy1, float scale) {
  constexpr int BM = MR * 32;
  constexpr int BN = 256;
  constexpr int LA = BM / 128;
  constexpr int LB = BN / 128;
  constexpr int LPT = LA + LB;
  constexpr int ABYTES = BM * 64;
  constexpr int BUFB = (BM + BN) * 64;
  constexpr int MH = MR / 2;
  __shared__ __align__(16) char smem[4 * BUFB];
  const int tid = threadIdx.x;
  const int lane = tid & 63, wid = tid >> 6;
  const int wm = wid >> 2, wn = wid & 3;

  const unsigned h = blockIdx.x;
  const bool sec = h >= nb0;
  const unsigned hh = sec ? h - nb0 : h;
  const unsigned nb = sec ? gridDim.x - nb0 : nb0;
  const unsigned gx = sec ? gx1 : gx0;
  const unsigned gy = sec ? gy1 : gy0;
  const short* Ap = sec ? A1 : A0;
  const short* Btp = sec ? B1 : B0;
  const float* bias = sec ? bias1 : bias0;
  void* Cptr = sec ? C1 : C0;
  short* C2p = sec ? D1 : D0;
  const int K = sec ? K1 : K0;
  const int lda = sec ? lda1 : lda0;
  const int ldb = sec ? ldb1 : ldb0;
  const int ldc = sec ? ldc1 : ldc0;
  const long long sA = sec ? sA1 : sA0;
  const long long sB = sec ? sB1 : sB0;
  const long long sC = sec ? sC1 : sC0;

  unsigned l = ((nb & 7u) == 0u) ? (hh & 7u) * (nb >> 3) + (hh >> 3) : hh;
  const unsigned bx = l % gx;
  const unsigned rem = l / gx;
  const unsigned by = rem % gy;
  const unsigned bz = rem / gy;

  const int zb = bz;
  const int m0 = by * BM, n0 = bx * BN;
  const char* Ab = (const char*)(Ap + (size_t)zb * sA);
  const char* Bb = (const char*)(Btp + (size_t)zb * sB);
  const size_t lda2 = (size_t)lda * 2, ldb2 = (size_t)ldb * 2;

  int s_r[2], s_cb[2];
#pragma unroll
  for (int j = 0; j < 2; ++j) {
    const int d = j * 8192 + tid * 16;
    const int line = d >> 7;
    s_r[j] = line * 2 + ((d >> 6) & 1);
    s_cb[j] = (d & 63) ^ ((line & 3) << 4);
  }

  f32x4 acc[MR][4] = {};
  const int frow = lane & 15, fkg = lane >> 4;

  int ra[MR], rb[4];
#pragma unroll
  for (int mf = 0; mf < MR; ++mf) {
    const int R = wm * (MR * 16) + mf * 16 + frow;
    ra[mf] = (R >> 1) * 128 + (R & 1) * 64 + ((fkg * 16) ^ (((R >> 1) & 3) << 4));
  }
#pragma unroll
  for (int nf = 0; nf < 4; ++nf) {
    const int R = wn * 64 + nf * 16 + frow;
    rb[nf] = (R >> 1) * 128 + (R & 1) * 64 + ((fkg * 16) ^ (((R >> 1) & 3) << 4));
  }

  const int NT = K >> 5;

#define STAGE_A(t)                                                       \
  {                                                                      \
    char* base_ = smem + ((t) & 3) * BUFB;                               \
    const size_t kb_ = (size_t)(t) * 64;                                 \
    _Pragma("unroll")                                                    \
    for (int j = 0; j < LA; ++j)                                         \
      gload16(Ab + (size_t)(m0 + s_r[j]) * lda2 + kb_ + s_cb[j],         \
              base_ + j * 8192 + tid * 16);                              \
  }
#define STAGE_B(t)                                                       \
  {                                                                      \
    char* base_ = smem + ((t) & 3) * BUFB + ABYTES;                      \
    const size_t kb_ = (size_t)(t) * 64;                                 \
    _Pragma("unroll")                                                    \
    for (int j = 0; j < LB; ++j)                                         \
      gload16(Bb + (size_t)(n0 + s_r[j]) * ldb2 + kb_ + s_cb[j],         \
              base_ + j * 8192 + tid * 16);                              \
  }

  STAGE_A(0); STAGE_B(0);
  STAGE_A(1); STAGE_B(1);
  STAGE_A(2); STAGE_B(2);
  waitcnt_vm<2 * LPT>();
  SB; __builtin_amdgcn_s_barrier(); SB;

  for (int t = 0; t < NT; ++t) {
    const char* la = smem + (t & 3) * BUFB;
    const char* lb = la + ABYTES;
    FragU fa[MR], fb[4];
    if (t + 3 < NT) STAGE_A(t + 3);
#pragma unroll
    for (int mf = 0; mf < MH; ++mf) fa[mf].s = *(const s16x8*)(la + ra[mf]);
#pragma unroll
    for (int nf = 0; nf < 4; ++nf) fb[nf].s = *(const s16x8*)(lb + rb[nf]);
    __builtin_amdgcn_s_barrier();
    asm volatile("s_waitcnt lgkmcnt(0)" ::: "memory");
    SB;
    __builtin_amdgcn_s_setprio(1);
#pragma unroll
    for (int mf = 0; mf < MH; ++mf)
#pragma unroll
      for (int nf = 0; nf < 4; ++nf)
        acc[mf][nf] = __builtin_amdgcn_mfma_f32_16x16x32_bf16(
            fa[mf].b, fb[nf].b, acc[mf][nf], 0, 0, 0);
    __builtin_amdgcn_s_setprio(0);
    __builtin_amdgcn_s_barrier();
    if (t + 3 < NT) STAGE_B(t + 3);
#pragma unroll
    for (int mf = MH; mf < MR; ++mf) fa[mf].s = *(const s16x8*)(la + ra[mf]);
    __builtin_amdgcn_s_barrier();
    asm volatile("s_waitcnt lgkmcnt(0)" ::: "memory");
    SB;
    __builtin_amdgcn_s_setprio(1);
#pragma unroll
    for (int mf = MH; mf < MR; ++mf)
#pragma unroll
      for (int nf = 0; nf < 4; ++nf)
        acc[mf][nf] = __builtin_amdgcn_mfma_f32_16x16x32_bf16(
            fa[mf].b, fb[nf].b, acc[mf][nf], 0, 0, 0);
    __builtin_amdgcn_s_setprio(0);
    if (t + 3 < NT) {
      waitcnt_vm<2 * LPT>();
    } else if (t + 2 < NT) {
      waitcnt_vm<LPT>();
    } else if (t + 1 < NT) {
      waitcnt_vm<0>();
    } else {
      break;
    }
    SB; __builtin_amdgcn_s_barrier(); SB;
  }
#undef STAGE_A
#undef STAGE_B

  const int rbase = (lane >> 4) * 4, cbase = lane & 15;
#pragma unroll
  for (int mf = 0; mf < MR; ++mf) {
#pragma unroll
    for (int nf = 0; nf < 4; ++nf) {
      const int gcol = n0 + wn * 64 + nf * 16 + cbase;
      float bn = (BIASMODE == 1) ? bias[gcol] : 0.f;
#pragma unroll
      for (int r = 0; r < 4; ++r) {
        const int grow = m0 + wm * (MR * 16) + mf * 16 + rbase + r;
        const size_t idx = (size_t)zb * sC + (size_t)grow * ldc + gcol;
        float v = acc[mf][nf][r];
        if constexpr (BIASMODE == 2) v += bias[grow]; else v += bn;
        if constexpr (OUTMODE == 0) {
          ((short*)Cptr)[idx] = f2bs(v);
        } else if constexpr (OUTMODE == 1) {
          __builtin_nontemporal_store(v, &((float*)Cptr)[idx]);
        } else if constexpr (OUTMODE == 2) {
          float p = 1.0f / (1.0f + __expf(-v * scale));
          __builtin_nontemporal_store(p, &((float*)Cptr)[idx]);
        } else {
          float p = 1.0f / (1.0f + __expf(-v * scale));
          __builtin_nontemporal_store(p, &((float*)Cptr)[idx]);
          C2p[idx] = f2bs(p);
        }
      }
    }
  }
}

// ---------------------------------------------------------------------------
// Fused scores+sigmoid+PV (flash-style, no softmax state needed).
// Per block: 128 Q-rows x D=512. Loop j-tiles of 128 K-rows:
//   S = Q@K^T (K=512, 3-buf depth-2 staging, vmcnt(2) steady)
//   sigmoid -> nt-store probs f32 -> P bf16 to swizzled LDS tile
//   ctx += P @ Vt-slice^T (K=128, V staged 3-buf depth-2)
// Next-j Q/K stages pre-issued at PV c==5 (vmcnt counts adjusted).
// ctx acc [128][512] f32 in registers; nt-stored at end.
// Two directions in one launch (dir sel by block id); per-half XCD remap.
// LDS: S bufs 3x16KB @0 | P 32KB @49152 | V bufs 3x16KB @81920 = 128KB.
// ---------------------------------------------------------------------------
__global__ __launch_bounds__(512, 2) void fused_sattn(
    const short* __restrict__ Q0, const short* __restrict__ K0,
    const short* __restrict__ V0, float* __restrict__ P0, float* __restrict__ C0,
    int LK0, long long sQ0, long long sK0, long long sV0, long long sP0,
    long long sC0, unsigned mt0, unsigned nb0,
    const short* __restrict__ Q1, const short* __restrict__ K1,
    const short* __restrict__ V1, float* __restrict__ P1, float* __restrict__ C1,
    int LK1, long long sQ1, long long sK1, long long sV1, long long sP1,
    long long sC1, unsigned mt1, float scale) {
  constexpr int PBASE = 49152;
  constexpr int VBASE = 81920;
  __shared__ __align__(16) char smem[131072];
  const int tid = threadIdx.x;
  const int lane = tid & 63, wid = tid >> 6;
  const int wm = wid >> 2, wn = wid & 3;
  const int frow = lane & 15, fkg = lane >> 4;

  const unsigned h = blockIdx.x;
  const bool sec = h >= nb0;
  const unsigned hh = sec ? h - nb0 : h;
  const unsigned nb = sec ? gridDim.x - nb0 : nb0;
  const unsigned mt = sec ? mt1 : mt0;
  const short* Qp = sec ? Q1 : Q0;
  const short* Kp = sec ? K1 : K0;
  const short* Vp = sec ? V1 : V0;
  float* Pp = sec ? P1 : P0;
  float* Cp = sec ? C1 : C0;
  const int LK = sec ? LK1 : LK0;
  const long long sQ = sec ? sQ1 : sQ0;
  const long long sK = sec ? sK1 : sK0;
  const long long sV = sec ? sV1 : sV0;
  const long long sP = sec ? sP1 : sP0;
  const long long sC = sec ? sC1 : sC0;

  unsigned l = ((nb & 7u) == 0u) ? (hh & 7u) * (nb >> 3) + (hh >> 3) : hh;
  const unsigned by = l % mt;
  const unsigned bz = l / mt;
  const int m0 = by * 128;
  const char* Qb = (const char*)(Qp + (size_t)bz * sQ);
  const char* Kb = (const char*)(Kp + (size_t)bz * sK);
  const char* Vb = (const char*)(Vp + (size_t)bz * sV);
  float* Pg = Pp + (size_t)bz * sP;
  float* Cg = Cp + (size_t)bz * sC;
  const int NJ = LK >> 7;
  const size_t ldv2 = (size_t)LK * 2;

  // staging maps
  int s_r, s_cb;
  { int d = tid * 16; int line = d >> 7;
    s_r = line * 2 + ((d >> 6) & 1); s_cb = (d & 63) ^ ((line & 3) << 4); }
  int s_r2[2], s_cb2[2];
#pragma unroll
  for (int jj = 0; jj < 2; ++jj) {
    int d = jj * 8192 + tid * 16; int line = d >> 7;
    s_r2[jj] = line * 2 + ((d >> 6) & 1); s_cb2[jj] = (d & 63) ^ ((line & 3) << 4);
  }

  // frag addresses
  int raq[4], rbk[2], rbv[4], rap[4];
#pragma unroll
  for (int mf = 0; mf < 4; ++mf) {
    const int R = wm * 64 + mf * 16 + frow;
    raq[mf] = (R >> 1) * 128 + (R & 1) * 64 + ((fkg * 16) ^ (((R >> 1) & 3) << 4));
    rap[mf] = PBASE + R * 256 + (((R & 7) << 4));  // XOR'd with kcb at use
  }
#pragma unroll
  for (int nf = 0; nf < 2; ++nf) {
    const int R = wn * 32 + nf * 16 + frow;
    rbk[nf] = 8192 + (R >> 1) * 128 + (R & 1) * 64 + ((fkg * 16) ^ (((R >> 1) & 3) << 4));
  }
#pragma unroll
  for (int nf = 0; nf < 4; ++nf) {
    const int R = wn * 64 + nf * 16 + frow;
    rbv[nf] = (R >> 1) * 128 + (R & 1) * 64 + ((fkg * 16) ^ (((R >> 1) & 3) << 4));
  }
  const int pswz = fkg * 16;  // + q*64, XOR'd with row swizzle (bits 4-6)

#define STAGE_S(ks, j0v)                                                   \
  {                                                                        \
    char* b_ = smem + ((ks) % 3) * 16384;                                  \
    gload16(Qb + (size_t)(m0 + s_r) * 2048 + (ks) * 64 + s_cb,             \
            b_ + tid * 16);                                                \
    gload16(Kb + (size_t)((j0v) + s_r) * 2048 + (ks) * 64 + s_cb,          \
            b_ + 8192 + tid * 16);                                         \
  }
#define STAGE_V(c, j0v)                                                    \
  {                                                                        \
    char* b_ = smem + VBASE + ((c) % 3) * 16384;                           \
    _Pragma("unroll")                                                      \
    for (int jj = 0; jj < 2; ++jj)                                         \
      gload16(Vb + (size_t)(((c) >> 2) * 256 + s_r2[jj]) * ldv2 +          \
                  (size_t)(j0v) * 2 + ((c) & 3) * 64 + s_cb2[jj],          \
              b_ + jj * 8192 + tid * 16);                                  \
  }

  f32x4 accc[4][8] = {};
  const int rbase = (lane >> 4) * 4, cbase = lane & 15;

  STAGE_S(0, 0); STAGE_S(1, 0);

  for (int jt = 0; jt < NJ; ++jt) {
    const int j0 = jt * 128;
    // ---- S phase ----
    waitcnt_vm<2>();
    SB; __builtin_amdgcn_s_barrier(); SB;
    f32x4 accs[4][2] = {};
#pragma unroll 4
    for (int ks = 0; ks < 16; ++ks) {
      if (ks < 14) STAGE_S(ks + 2, j0);
      const char* bp = smem + (ks % 3) * 16384;
      FragU fq[4], fk[2];
#pragma unroll
      for (int mf = 0; mf < 4; ++mf) fq[mf].s = *(const s16x8*)(bp + raq[mf]);
#pragma unroll
      for (int nf = 0; nf < 2; ++nf) fk[nf].s = *(const s16x8*)(bp + rbk[nf]);
      asm volatile("s_waitcnt lgkmcnt(0)" ::: "memory");
      SB;
      __builtin_amdgcn_s_setprio(1);
#pragma unroll
      for (int mf = 0; mf < 4; ++mf)
#pragma unroll
        for (int nf = 0; nf < 2; ++nf)
          accs[mf][nf] = __builtin_amdgcn_mfma_f32_16x16x32_bf16(
              fq[mf].b, fk[nf].b, accs[mf][nf], 0, 0, 0);
      __builtin_amdgcn_s_setprio(0);
      if (ks < 14) waitcnt_vm<2>();
      else if (ks == 14) waitcnt_vm<0>();
      else break;
      SB; __builtin_amdgcn_s_barrier(); SB;
    }
    // ---- sigmoid + probs store + P_lds write ----
#pragma unroll
    for (int mf = 0; mf < 4; ++mf)
#pragma unroll
      for (int nf = 0; nf < 2; ++nf)
#pragma unroll
        for (int r = 0; r < 4; ++r) {
          const float p = 1.0f / (1.0f + __expf(-accs[mf][nf][r] * scale));
          const int row = wm * 64 + mf * 16 + rbase + r;
          const int col = wn * 32 + nf * 16 + cbase;
          __builtin_nontemporal_store(
              p, &Pg[(size_t)(m0 + row) * LK + j0 + col]);
          *(short*)(smem + PBASE + row * 256 +
                    ((2 * col) ^ ((row & 7) << 4))) = f2bs(p);
        }
    STAGE_V(0, j0); STAGE_V(1, j0);
    SB;
    asm volatile("s_waitcnt lgkmcnt(0)" ::: "memory");
    __builtin_amdgcn_s_barrier(); SB;
    // ---- PV phase ----
    const bool pre = (jt + 1 < NJ);
#pragma unroll
    for (int c = 0; c < 8; ++c) {
      if (c < 6) STAGE_V(c + 2, j0);
      if (c == 5 && pre) { STAGE_S(0, j0 + 128); STAGE_S(1, j0 + 128); }
      const int q = c & 3, hf = c >> 2;
      const char* vb = smem + VBASE + (c % 3) * 16384;
      FragU pa[4], vv[4];
#pragma unroll
      for (int mf = 0; mf < 4; ++mf)
        pa[mf].s = *(const s16x8*)(smem + (rap[mf] ^ (q * 64 + pswz)));
#pragma unroll
      for (int nf = 0; nf < 4; ++nf) vv[nf].s = *(const s16x8*)(vb + rbv[nf]);
      asm volatile("s_waitcnt lgkmcnt(0)" ::: "memory");
      SB;
      __builtin_amdgcn_s_setprio(1);
#pragma unroll
      for (int mf = 0; mf < 4; ++mf)
#pragma unroll
        for (int nf = 0; nf < 4; ++nf)
          accc[mf][hf * 4 + nf] = __builtin_amdgcn_mfma_f32_16x16x32_bf16(
              pa[mf].b, vv[nf].b, accc[mf][hf * 4 + nf], 0, 0, 0);
      __builtin_amdgcn_s_setprio(0);
      if (c < 5) {
        waitcnt_vm<2>();
      } else if (c == 5) {
        if (pre) waitcnt_vm<6>(); else waitcnt_vm<2>();
      } else if (c == 6) {
        if (pre) waitcnt_vm<4>(); else waitcnt_vm<0>();
      } else {
        break;
      }
      SB; __builtin_amdgcn_s_barrier(); SB;
    }
    SB; __builtin_amdgcn_s_barrier(); SB;  // P_lds reuse fence for next jt
  }
#undef STAGE_S
#undef STAGE_V

  // ---- ctx epilogue ----
#pragma unroll
  for (int mf = 0; mf < 4; ++mf)
#pragma unroll
    for (int g = 0; g < 8; ++g) {
      const int gcol = (g >> 2) * 256 + wn * 64 + (g & 3) * 16 + cbase;
#pragma unroll
      for (int r = 0; r < 4; ++r) {
        const int grow = m0 + wm * 64 + mf * 16 + rbase + r;
        __builtin_nontemporal_store(
            accc[mf][g][r], &Cg[(size_t)grow * 512 + gcol]);
      }
    }
}

// ---------------------------------------------------------------------------
// Fallback (tierB only): gload-staged 128x128 BK=64 GEMM, AF32 supported.
// ---------------------------------------------------------------------------
template <int OUTMODE, int BIASMODE, int AF32>
__global__ __launch_bounds__(256) void gemm_bt(
    const void* __restrict__ Aptr, const short* __restrict__ Btp,
    const float* __restrict__ bias, void* __restrict__ Cptr,
    short* __restrict__ C2p,
    int K, int lda, int ldb, int ldc,
    long long sA, long long sB, long long sC, float scale) {
  __shared__ __align__(16) short lsA[128 * 64];
  __shared__ __align__(16) short lsB[128 * 64];
  const int tid = threadIdx.x;
  const int lane = tid & 63, wid = tid >> 6;
  const int zb = blockIdx.z;
  const int m0 = blockIdx.y * 128, n0 = blockIdx.x * 128;
  const short* Ab = AF32 ? nullptr : (const short*)Aptr + (size_t)zb * sA;
  const float* Af = AF32 ? (const float*)Aptr + (size_t)zb * sA : nullptr;
  const short* Bt = Btp + (size_t)zb * sB;

  f32x4 acc[4][4] = {};
  const int woffM = (wid >> 1) * 64, woffN = (wid & 1) * 64;
  const int frow = lane & 15, fkg = lane >> 4;

  for (int k0 = 0; k0 < K; k0 += 64) {
    if (k0) __syncthreads();
    if constexpr (!AF32) {
#pragma unroll
      for (int i = 0; i < 4; ++i) {
        const int f = i * 4096 + tid * 16;
        const int row = f >> 7, colb = f & 127;
        gload16((const char*)Ab + ((size_t)(m0 + row) * lda + k0) * 2 + colb,
                (char*)lsA + f);
      }
    } else {
#pragma unroll
      for (int i = 0; i < 8; ++i) {
        int f = tid + i * 256;
        int row = f >> 4, c4 = f & 15;
        f32x4 v = *(const f32x4*)&Af[(size_t)(m0 + row) * lda + k0 + c4 * 4];
        union { short s[4]; unsigned long long q; } cv;
#pragma unroll
        for (int j = 0; j < 4; ++j) cv.s[j] = f2bs(v[j]);
        *(unsigned long long*)&lsA[row * 64 + c4 * 4] = cv.q;
      }
    }
#pragma unroll
    for (int i = 0; i < 4; ++i) {
      const int f = i * 4096 + tid * 16;
      const int row = f >> 7, colb = f & 127;
      gload16((const char*)Bt + ((size_t)(n0 + row) * ldb + k0) * 2 + colb,
              (char*)lsB + f);
    }
    __syncthreads();
#pragma unroll
    for (int kk = 0; kk < 2; ++kk) {
      const int kb = kk * 32 + fkg * 8;
      FragU fa[4], fb[4];
#pragma unroll
      for (int mf = 0; mf < 4; ++mf)
        fa[mf].s = *(const s16x8*)&lsA[(woffM + mf * 16 + frow) * 64 + kb];
#pragma unroll
      for (int nf = 0; nf < 4; ++nf)
        fb[nf].s = *(const s16x8*)&lsB[(woffN + nf * 16 + frow) * 64 + kb];
#pragma unroll
      for (int mf = 0; mf < 4; ++mf)
#pragma unroll
        for (int nf = 0; nf < 4; ++nf)
          acc[mf][nf] = __builtin_amdgcn_mfma_f32_16x16x32_bf16(
              fa[mf].b, fb[nf].b, acc[mf][nf], 0, 0, 0);
    }
  }

  const int rbase = (lane >> 4) * 4, cbase = lane & 15;
#pragma unroll
  for (int mf = 0; mf < 4; ++mf) {
#pragma unroll
    for (int nf = 0; nf < 4; ++nf) {
      const int gcol = n0 + woffN + nf * 16 + cbase;
      float bn = (BIASMODE == 1) ? bias[gcol] : 0.f;
#pragma unroll
      for (int r = 0; r < 4; ++r) {
        const int grow = m0 + woffM + mf * 16 + rbase + r;
        const size_t idx = (size_t)zb * sC + (size_t)grow * ldc + gcol;
        float v = acc[mf][nf][r];
        if constexpr (BIASMODE == 2) v += bias[grow]; else v += bn;
        if constexpr (OUTMODE == 0) {
          ((short*)Cptr)[idx] = f2bs(v);
        } else if constexpr (OUTMODE == 1) {
          ((float*)Cptr)[idx] = v;
        } else if constexpr (OUTMODE == 2) {
          ((float*)Cptr)[idx] = 1.0f / (1.0f + __expf(-v * scale));
        } else {
          float p = 1.0f / (1.0f + __expf(-v * scale));
          ((float*)Cptr)[idx] = p;
          C2p[idx] = f2bs(p);
        }
      }
    }
  }
}

extern "C" void kernel_launch(void* const* d_in, const int* in_sizes, int n_in,
                              void* d_out, int out_size, void* d_ws, size_t ws_size,
                              hipStream_t stream) {
  const float* in1 = (const float*)d_in[0];   // [16][512][2048]
  const float* in2 = (const float*)d_in[1];   // [16][768][1024]
  const float* Wq1 = (const float*)d_in[2];  const float* bq1 = (const float*)d_in[3];
  const float* Wk1 = (const float*)d_in[4];  const float* bk1 = (const float*)d_in[5];
  const float* Wv1 = (const float*)d_in[6];  const float* bv1 = (const float*)d_in[7];
  const float* Wq2 = (const float*)d_in[8];  const float* bq2 = (const float*)d_in[9];
  const float* Wk2 = (const float*)d_in[10]; const float* bk2 = (const float*)d_in[11];
  const float* Wv2 = (const float*)d_in[12]; const float* bv2 = (const float*)d_in[13];

  float* out = (float*)d_out;
  float* ctx2   = out;                                      // [16][2048][512]
  float* probs2 = out + (size_t)16 * 2048 * 512;            // [16][2048][1024]
  float* ctx1   = probs2 + (size_t)16 * 2048 * 1024;        // [16][1024][512]
  float* probs1 = ctx1 + (size_t)16 * 1024 * 512;           // [16][1024][2048]

  char* ws = (char*)d_ws;
  constexpr size_t O_WQ1T = 0;
  constexpr size_t O_WK1T = O_WQ1T + (size_t)512 * 512 * 2;
  constexpr size_t O_WV1T = O_WK1T + (size_t)512 * 512 * 2;
  constexpr size_t O_WQ2T = O_WV1T + (size_t)512 * 512 * 2;
  constexpr size_t O_WK2T = O_WQ2T + (size_t)768 * 512 * 2;
  constexpr size_t O_WV2T = O_WK2T + (size_t)768 * 512 * 2;
  constexpr size_t O_B1   = O_WV2T + (size_t)768 * 512 * 2;
  constexpr size_t O_B2   = O_B1 + 4096;
  constexpr size_t O_QK1  = O_B2 + 4096;                          // [32768][1024]
  constexpr size_t O_V1T  = O_QK1 + (size_t)32768 * 1024 * 2;     // [16][512][2048]
  constexpr size_t O_QK2  = O_V1T + (size_t)16 * 512 * 2048 * 2;  // [16384][1024]
  constexpr size_t O_V2T  = O_QK2 + (size_t)16384 * 1024 * 2;     // [16][512][1024]
  constexpr size_t O_X1B  = O_V2T + (size_t)16 * 512 * 1024 * 2;  // [32768][512]
  constexpr size_t O_X2B  = O_X1B + (size_t)32768 * 512 * 2;      // [16384][768]
  constexpr size_t NEED_B = O_X2B + (size_t)16384 * 768 * 2;

  short* wq1t = (short*)(ws + O_WQ1T);
  short* wk1t = (short*)(ws + O_WK1T);
  short* wv1t = (short*)(ws + O_WV1T);
  short* wq2t = (short*)(ws + O_WQ2T);
  short* wk2t = (short*)(ws + O_WK2T);
  short* wv2t = (short*)(ws + O_WV2T);
  float* b1c  = (float*)(ws + O_B1);
  float* b2c  = (float*)(ws + O_B2);
  short* qk1  = (short*)(ws + O_QK1);
  short* v1t  = (short*)(ws + O_V1T);
  short* qk2  = (short*)(ws + O_QK2);
  short* v2t  = (short*)(ws + O_V2T);
  short* x1b  = (short*)(ws + O_X1B);
  short* x2b  = (short*)(ws + O_X2B);

  const bool tierA = ws_size >= NEED_B;
  if (!tierA) { x1b = (short*)probs1; x2b = (short*)probs2; }

  dim3 blk256(256), blk512(512);
  dim3 blkT(32, 8);

  // ---- stage 0 ----
  transpose_cvt<<<dim3(64, 8, 16), blkT, 0, stream>>>(in1, x1b, 512, 2048);
  transpose_cvt<<<dim3(32, 12, 16), blkT, 0, stream>>>(in2, x2b, 768, 1024);
  prep_weights<<<dim3(16, 12, 7), blkT, 0, stream>>>(
      Wq1, Wk1, Wv1, Wq2, Wk2, Wv2, wq1t, wk1t, wv1t, wq2t, wk2t, wv2t,
      bq1, bk1, bq2, bk2, b1c, b2c);

  const float scale = 0.04419417382415922f;  // 1/sqrt(512)
  const short* q1p = qk1;        // lda 1024
  const short* k1p = qk1 + 512;
  const short* q2p = qk2;
  const short* k2p = qk2 + 512;

  if (tierA) {
    // ---- P1: qk1 + qk2 ----
    gemm8d<0, 1, 8><<<dim3(768), blk512, 0, stream>>>(
        x1b, wq1t, b1c, qk1, nullptr, 512, 512, 512, 1024, 0, 0, 0,
        4u, 128u, 512u,
        x2b, wq2t, b2c, qk2, nullptr, 768, 768, 768, 1024, 0, 0, 0,
        4u, 64u, 1.f);
    // ---- P2: v1t + v2t ----
    gemm8d<0, 2, 4><<<dim3(768), blk512, 0, stream>>>(
        wv1t, x1b, bv1, v1t, nullptr, 512, 512, 512, 2048,
        0, (long long)2048 * 512, (long long)512 * 2048,
        8u, 4u, 512u,
        wv2t, x2b, bv2, v2t, nullptr, 768, 768, 768, 1024,
        0, (long long)1024 * 768, (long long)512 * 1024,
        4u, 4u, 1.f);
    // ---- P3: fused scores+sigmoid+PV (both directions) ----
    fused_sattn<<<dim3(384), blk512, 0, stream>>>(
        q2p, k1p, v1t, probs1, ctx1, 2048,
        (long long)1024 * 1024, (long long)2048 * 1024, (long long)512 * 2048,
        (long long)1024 * 2048, (long long)1024 * 512, 8u, 128u,
        q1p, k2p, v2t, probs2, ctx2, 1024,
        (long long)2048 * 1024, (long long)1024 * 1024, (long long)512 * 1024,
        (long long)2048 * 1024, (long long)2048 * 512, 16u,
        scale);
  } else {
    gemm_bt<0, 1, 0><<<dim3(8, 256, 1), blk256, 0, stream>>>(
        x1b, wq1t, b1c, qk1, nullptr, 512, 512, 512, 1024, 0, 0, 0, 1.f);
    gemm_bt<0, 1, 0><<<dim3(8, 128, 1), blk256, 0, stream>>>(
        x2b, wq2t, b2c, qk2, nullptr, 768, 768, 768, 1024, 0, 0, 0, 1.f);
    gemm_bt<0, 2, 0><<<dim3(16, 4, 16), blk256, 0, stream>>>(
        wv1t, x1b, bv1, v1t, nullptr, 512, 512, 512, 2048,
        0, (long long)2048 * 512, (long long)512 * 2048, 1.f);
    gemm_bt<0, 2, 0><<<dim3(8, 4, 16), blk256, 0, stream>>>(
        wv2t, x2b, bv2, v2t, nullptr, 768, 768, 768, 1024,
        0, (long long)1024 * 768, (long long)512 * 1024, 1.f);
    gemm_bt<2, 0, 0><<<dim3(16, 8, 16), blk256, 0, stream>>>(
        q2p, k1p, nullptr, probs1, nullptr, 512, 1024, 1024, 2048,
        (long long)1024 * 1024, (long long)2048 * 1024, (long long)1024 * 2048, scale);
    gemm_bt<2, 0, 0><<<dim3(8, 16, 16), blk256, 0, stream>>>(
        q1p, k2p, nullptr, probs2, nullptr, 512, 1024, 1024, 1024,
        (long long)2048 * 1024, (long long)1024 * 1024, (long long)2048 * 1024, scale);
    gemm_bt<1, 0, 1><<<dim3(4, 8, 16), blk256, 0, stream>>>(
        probs1, v1t, nullptr, ctx1, nullptr, 2048, 2048, 2048, 512,
        (long long)1024 * 2048, (long long)512 * 2048, (long long)1024 * 512, 1.f);
    gemm_bt<1, 0, 1><<<dim3(4, 16, 16), blk256, 0, stream>>>(
        probs2, v2t, nullptr, ctx2, nullptr, 1024, 1024, 1024, 512,
        (long long)2048 * 1024, (long long)512 * 1024, (long long)2048 * 512, 1.f);
  }
}

// Round 11
// 470.262 us; speedup vs baseline: 1.0530x; 1.0530x over previous
//
#include <hip/hip_runtime.h>
#include <hip/hip_bf16.h>

#define DEVFN __device__ __forceinline__
#define SB __builtin_amdgcn_sched_barrier(0)

typedef __attribute__((ext_vector_type(4))) float f32x4;
typedef __attribute__((ext_vector_type(8))) short s16x8;
typedef __attribute__((ext_vector_type(2))) short s16x2;
typedef __attribute__((ext_vector_type(8))) __bf16 bf16x8;

union FragU { s16x8 s; bf16x8 b; };

DEVFN short f2bs(float x) {
  union { __hip_bfloat16 h; short s; } u;
  u.h = __float2bfloat16(x);
  return u.s;
}

DEVFN void gload16(const void* g, void* l) {
  __builtin_amdgcn_global_load_lds(
      (const __attribute__((address_space(1))) void*)g,
      (__attribute__((address_space(3))) void*)l, 16, 0, 0);
}

template <int N> DEVFN void waitcnt_vm() {
  if constexpr (N == 0) asm volatile("s_waitcnt vmcnt(0)" ::: "memory");
  else if constexpr (N == 2) asm volatile("s_waitcnt vmcnt(2)" ::: "memory");
  else if constexpr (N == 3) asm volatile("s_waitcnt vmcnt(3)" ::: "memory");
  else if constexpr (N == 4) asm volatile("s_waitcnt vmcnt(4)" ::: "memory");
  else if constexpr (N == 6) asm volatile("s_waitcnt vmcnt(6)" ::: "memory");
  else if constexpr (N == 8) asm volatile("s_waitcnt vmcnt(8)" ::: "memory");
  else static_assert(N == 0, "unsupported vmcnt");
}

// in: [Z][C][L] f32 -> out: [Z][L][C] bf16.
__global__ __launch_bounds__(256) void transpose_cvt(
    const float* __restrict__ in, short* __restrict__ out, int C, int L) {
  __shared__ float tile[64][33];
  const int l0 = blockIdx.x * 32, c0 = blockIdx.y * 64;
  const size_t base = (size_t)blockIdx.z * C * L;
  const int tx = threadIdx.x, ty = threadIdx.y;
#pragma unroll
  for (int i = ty; i < 64; i += 8)
    tile[i][tx] = in[base + (size_t)(c0 + i) * L + l0 + tx];
  __syncthreads();
#pragma unroll
  for (int i = ty; i < 32; i += 8) {
    s16x2 v;
    v[0] = f2bs(tile[2 * tx][i]);
    v[1] = f2bs(tile[2 * tx + 1][i]);
    *(s16x2*)&out[base + (size_t)(l0 + i) * C + c0 + 2 * tx] = v;
  }
}

// All six weight transposes + both bias concats, one launch.
__global__ __launch_bounds__(256) void prep_weights(
    const float* __restrict__ Wq1, const float* __restrict__ Wk1,
    const float* __restrict__ Wv1, const float* __restrict__ Wq2,
    const float* __restrict__ Wk2, const float* __restrict__ Wv2,
    short* wq1t, short* wk1t, short* wv1t,
    short* wq2t, short* wk2t, short* wv2t,
    const float* __restrict__ bq1, const float* __restrict__ bk1,
    const float* __restrict__ bq2, const float* __restrict__ bk2,
    float* b1c, float* b2c) {
  const int z = blockIdx.z;
  if (z == 6) {
    if (blockIdx.y != 0 || blockIdx.x >= 8) return;
    const int bx = blockIdx.x;
    const int tid = threadIdx.y * 32 + threadIdx.x;
    const int i = (bx & 3) * 256 + tid;
    const float* s = (bx < 4) ? ((i < 512) ? bq1 : bk1)
                              : ((i < 512) ? bq2 : bk2);
    float* d = (bx < 4) ? b1c : b2c;
    d[i] = s[i & 511];
    return;
  }
  const float* W; short* O; int C;
  switch (z) {
    case 0: W = Wq1; O = wq1t; C = 512; break;
    case 1: W = Wk1; O = wk1t; C = 512; break;
    case 2: W = Wv1; O = wv1t; C = 512; break;
    case 3: W = Wq2; O = wq2t; C = 768; break;
    case 4: W = Wk2; O = wk2t; C = 768; break;
    default: W = Wv2; O = wv2t; C = 768; break;
  }
  if (blockIdx.y * 64 >= (unsigned)C) return;
  const int L = 512;
  __shared__ float tile[64][33];
  const int l0 = blockIdx.x * 32, c0 = blockIdx.y * 64;
  const int tx = threadIdx.x, ty = threadIdx.y;
#pragma unroll
  for (int i = ty; i < 64; i += 8)
    tile[i][tx] = W[(size_t)(c0 + i) * L + l0 + tx];
  __syncthreads();
#pragma unroll
  for (int i = ty; i < 32; i += 8) {
    s16x2 v;
    v[0] = f2bs(tile[2 * tx][i]);
    v[1] = f2bs(tile[2 * tx + 1][i]);
    *(s16x2*)&O[(size_t)(l0 + i) * C + c0 + 2 * tx] = v;
  }
}

// Per-GEMM parameters for the quad launch.
struct GArg {
  const short* A; const short* B; const float* bias; short* C;
  int K, lda, ldb, ldc;
  long long sA, sB, sC;
  unsigned gx, gy, nb;   // tile grid + segment block count (nb % 8 == 0)
  int bm;                // bias mode: 0 none, 1 per-n, 2 per-m
};

// ---------------------------------------------------------------------------
// Quad-GEMM launch: four independent bf16-out GEMMs (MR=8 256x256 template),
// one grid; block ranges select the segment; per-segment XCD remap.
// Pipeline identical to the verified gemm8d (depth-3, 4 bufs, counted vmcnt,
// 2-phase K-step, setprio).
// ---------------------------------------------------------------------------
__global__ __launch_bounds__(512, 2) void gemm8q(
    GArg g0, GArg g1, GArg g2, GArg g3) {
  constexpr int MR = 8;
  constexpr int BM = 256, BN = 256;
  constexpr int LA = 2, LB = 2, LPT = 4;
  constexpr int ABYTES = BM * 64;
  constexpr int BUFB = (BM + BN) * 64;
  constexpr int MH = MR / 2;
  __shared__ __align__(16) char smem[4 * BUFB];
  const int tid = threadIdx.x;
  const int lane = tid & 63, wid = tid >> 6;
  const int wm = wid >> 2, wn = wid & 3;

  // ---- segment select ----
  const unsigned h = blockIdx.x;
  GArg ga; unsigned hh;
  const unsigned b0 = g0.nb, b1 = b0 + g1.nb, b2 = b1 + g2.nb;
  if (h < b0)      { ga = g0; hh = h; }
  else if (h < b1) { ga = g1; hh = h - b0; }
  else if (h < b2) { ga = g2; hh = h - b1; }
  else             { ga = g3; hh = h - b2; }

  // ---- per-segment XCD remap (nb % 8 == 0 guaranteed) ----
  const unsigned nb = ga.nb;
  unsigned l = (hh & 7u) * (nb >> 3) + (hh >> 3);
  const unsigned bx = l % ga.gx;
  const unsigned rem = l / ga.gx;
  const unsigned by = rem % ga.gy;
  const unsigned bz = rem / ga.gy;

  const int m0 = by * BM, n0 = bx * BN;
  const char* Ab = (const char*)(ga.A + (size_t)bz * ga.sA);
  const char* Bb = (const char*)(ga.B + (size_t)bz * ga.sB);
  const size_t lda2 = (size_t)ga.lda * 2, ldb2 = (size_t)ga.ldb * 2;

  int s_r[2], s_cb[2];
#pragma unroll
  for (int j = 0; j < 2; ++j) {
    const int d = j * 8192 + tid * 16;
    const int line = d >> 7;
    s_r[j] = line * 2 + ((d >> 6) & 1);
    s_cb[j] = (d & 63) ^ ((line & 3) << 4);
  }

  f32x4 acc[MR][4] = {};
  const int frow = lane & 15, fkg = lane >> 4;

  int ra[MR], rb[4];
#pragma unroll
  for (int mf = 0; mf < MR; ++mf) {
    const int R = wm * (MR * 16) + mf * 16 + frow;
    ra[mf] = (R >> 1) * 128 + (R & 1) * 64 + ((fkg * 16) ^ (((R >> 1) & 3) << 4));
  }
#pragma unroll
  for (int nf = 0; nf < 4; ++nf) {
    const int R = wn * 64 + nf * 16 + frow;
    rb[nf] = (R >> 1) * 128 + (R & 1) * 64 + ((fkg * 16) ^ (((R >> 1) & 3) << 4));
  }

  const int NT = ga.K >> 5;

#define STAGE_A(t)                                                       \
  {                                                                      \
    char* base_ = smem + ((t) & 3) * BUFB;                               \
    const size_t kb_ = (size_t)(t) * 64;                                 \
    _Pragma("unroll")                                                    \
    for (int j = 0; j < LA; ++j)                                         \
      gload16(Ab + (size_t)(m0 + s_r[j]) * lda2 + kb_ + s_cb[j],         \
              base_ + j * 8192 + tid * 16);                              \
  }
#define STAGE_B(t)                                                       \
  {                                                                      \
    char* base_ = smem + ((t) & 3) * BUFB + ABYTES;                      \
    const size_t kb_ = (size_t)(t) * 64;                                 \
    _Pragma("unroll")                                                    \
    for (int j = 0; j < LB; ++j)                                         \
      gload16(Bb + (size_t)(n0 + s_r[j]) * ldb2 + kb_ + s_cb[j],         \
              base_ + j * 8192 + tid * 16);                              \
  }

  STAGE_A(0); STAGE_B(0);
  STAGE_A(1); STAGE_B(1);
  STAGE_A(2); STAGE_B(2);
  waitcnt_vm<2 * LPT>();
  SB; __builtin_amdgcn_s_barrier(); SB;

  for (int t = 0; t < NT; ++t) {
    const char* la = smem + (t & 3) * BUFB;
    const char* lb = la + ABYTES;
    FragU fa[MR], fb[4];
    if (t + 3 < NT) STAGE_A(t + 3);
#pragma unroll
    for (int mf = 0; mf < MH; ++mf) fa[mf].s = *(const s16x8*)(la + ra[mf]);
#pragma unroll
    for (int nf = 0; nf < 4; ++nf) fb[nf].s = *(const s16x8*)(lb + rb[nf]);
    __builtin_amdgcn_s_barrier();
    asm volatile("s_waitcnt lgkmcnt(0)" ::: "memory");
    SB;
    __builtin_amdgcn_s_setprio(1);
#pragma unroll
    for (int mf = 0; mf < MH; ++mf)
#pragma unroll
      for (int nf = 0; nf < 4; ++nf)
        acc[mf][nf] = __builtin_amdgcn_mfma_f32_16x16x32_bf16(
            fa[mf].b, fb[nf].b, acc[mf][nf], 0, 0, 0);
    __builtin_amdgcn_s_setprio(0);
    __builtin_amdgcn_s_barrier();
    if (t + 3 < NT) STAGE_B(t + 3);
#pragma unroll
    for (int mf = MH; mf < MR; ++mf) fa[mf].s = *(const s16x8*)(la + ra[mf]);
    __builtin_amdgcn_s_barrier();
    asm volatile("s_waitcnt lgkmcnt(0)" ::: "memory");
    SB;
    __builtin_amdgcn_s_setprio(1);
#pragma unroll
    for (int mf = MH; mf < MR; ++mf)
#pragma unroll
      for (int nf = 0; nf < 4; ++nf)
        acc[mf][nf] = __builtin_amdgcn_mfma_f32_16x16x32_bf16(
            fa[mf].b, fb[nf].b, acc[mf][nf], 0, 0, 0);
    __builtin_amdgcn_s_setprio(0);
    if (t + 3 < NT) {
      waitcnt_vm<2 * LPT>();
    } else if (t + 2 < NT) {
      waitcnt_vm<LPT>();
    } else if (t + 1 < NT) {
      waitcnt_vm<0>();
    } else {
      break;
    }
    SB; __builtin_amdgcn_s_barrier(); SB;
  }
#undef STAGE_A
#undef STAGE_B

  const int rbase = (lane >> 4) * 4, cbase = lane & 15;
#pragma unroll
  for (int mf = 0; mf < MR; ++mf) {
#pragma unroll
    for (int nf = 0; nf < 4; ++nf) {
      const int gcol = n0 + wn * 64 + nf * 16 + cbase;
      const float bn = (ga.bm == 1) ? ga.bias[gcol] : 0.f;
#pragma unroll
      for (int r = 0; r < 4; ++r) {
        const int grow = m0 + wm * (MR * 16) + mf * 16 + rbase + r;
        float v = acc[mf][nf][r] + bn;
        if (ga.bm == 2) v += ga.bias[grow];
        ga.C[(size_t)bz * ga.sC + (size_t)grow * ga.ldc + gcol] = f2bs(v);
      }
    }
  }
}

// ---------------------------------------------------------------------------
// Dual-GEMM launch (R8-verified): deep-pipelined 256xBN, used for P3/P4.
// OUTMODE: 0=bf16, 1=f32(nt), 2=sigmoid f32(nt), 3=sigmoid f32(nt)+bf16 D
// ---------------------------------------------------------------------------
template <int OUTMODE, int BIASMODE, int MR>
__global__ __launch_bounds__(512, 2) void gemm8d(
    const short* __restrict__ A0, const short* __restrict__ B0,
    const float* __restrict__ bias0, void* __restrict__ C0, short* __restrict__ D0,
    int K0, int lda0, int ldb0, int ldc0,
    long long sA0, long long sB0, long long sC0,
    unsigned gx0, unsigned gy0, unsigned nb0,
    const short* __restrict__ A1, const short* __restrict__ B1,
    const float* __restrict__ bias1, void* __restrict__ C1, short* __restrict__ D1,
    int K1, int lda1, int ldb1, int ldc1,
    long long sA1, long long sB1, long long sC1,
    unsigned gx1, unsigned gy1, float scale) {
  constexpr int BM = MR * 32;
  constexpr int BN = 256;
  constexpr int LA = BM / 128;
  constexpr int LB = BN / 128;
  constexpr int LPT = LA + LB;
  constexpr int ABYTES = BM * 64;
  constexpr int BUFB = (BM + BN) * 64;
  constexpr int MH = MR / 2;
  __shared__ __align__(16) char smem[4 * BUFB];
  const int tid = threadIdx.x;
  const int lane = tid & 63, wid = tid >> 6;
  const int wm = wid >> 2, wn = wid & 3;

  const unsigned h = blockIdx.x;
  const bool sec = h >= nb0;
  const unsigned hh = sec ? h - nb0 : h;
  const unsigned nb = sec ? gridDim.x - nb0 : nb0;
  const unsigned gx = sec ? gx1 : gx0;
  const unsigned gy = sec ? gy1 : gy0;
  const short* Ap = sec ? A1 : A0;
  const short* Btp = sec ? B1 : B0;
  const float* bias = sec ? bias1 : bias0;
  void* Cptr = sec ? C1 : C0;
  short* C2p = sec ? D1 : D0;
  const int K = sec ? K1 : K0;
  const int lda = sec ? lda1 : lda0;
  const int ldb = sec ? ldb1 : ldb0;
  const int ldc = sec ? ldc1 : ldc0;
  const long long sA = sec ? sA1 : sA0;
  const long long sB = sec ? sB1 : sB0;
  const long long sC = sec ? sC1 : sC0;

  unsigned l = ((nb & 7u) == 0u) ? (hh & 7u) * (nb >> 3) + (hh >> 3) : hh;
  const unsigned bx = l % gx;
  const unsigned rem = l / gx;
  const unsigned by = rem % gy;
  const unsigned bz = rem / gy;

  const int zb = bz;
  const int m0 = by * BM, n0 = bx * BN;
  const char* Ab = (const char*)(Ap + (size_t)zb * sA);
  const char* Bb = (const char*)(Btp + (size_t)zb * sB);
  const size_t lda2 = (size_t)lda * 2, ldb2 = (size_t)ldb * 2;

  int s_r[2], s_cb[2];
#pragma unroll
  for (int j = 0; j < 2; ++j) {
    const int d = j * 8192 + tid * 16;
    const int line = d >> 7;
    s_r[j] = line * 2 + ((d >> 6) & 1);
    s_cb[j] = (d & 63) ^ ((line & 3) << 4);
  }

  f32x4 acc[MR][4] = {};
  const int frow = lane & 15, fkg = lane >> 4;

  int ra[MR], rb[4];
#pragma unroll
  for (int mf = 0; mf < MR; ++mf) {
    const int R = wm * (MR * 16) + mf * 16 + frow;
    ra[mf] = (R >> 1) * 128 + (R & 1) * 64 + ((fkg * 16) ^ (((R >> 1) & 3) << 4));
  }
#pragma unroll
  for (int nf = 0; nf < 4; ++nf) {
    const int R = wn * 64 + nf * 16 + frow;
    rb[nf] = (R >> 1) * 128 + (R & 1) * 64 + ((fkg * 16) ^ (((R >> 1) & 3) << 4));
  }

  const int NT = K >> 5;

#define STAGE_A(t)                                                       \
  {                                                                      \
    char* base_ = smem + ((t) & 3) * BUFB;                               \
    const size_t kb_ = (size_t)(t) * 64;                                 \
    _Pragma("unroll")                                                    \
    for (int j = 0; j < LA; ++j)                                         \
      gload16(Ab + (size_t)(m0 + s_r[j]) * lda2 + kb_ + s_cb[j],         \
              base_ + j * 8192 + tid * 16);                              \
  }
#define STAGE_B(t)                                                       \
  {                                                                      \
    char* base_ = smem + ((t) & 3) * BUFB + ABYTES;                      \
    const size_t kb_ = (size_t)(t) * 64;                                 \
    _Pragma("unroll")                                                    \
    for (int j = 0; j < LB; ++j)                                         \
      gload16(Bb + (size_t)(n0 + s_r[j]) * ldb2 + kb_ + s_cb[j],         \
              base_ + j * 8192 + tid * 16);                              \
  }

  STAGE_A(0); STAGE_B(0);
  STAGE_A(1); STAGE_B(1);
  STAGE_A(2); STAGE_B(2);
  waitcnt_vm<2 * LPT>();
  SB; __builtin_amdgcn_s_barrier(); SB;

  for (int t = 0; t < NT; ++t) {
    const char* la = smem + (t & 3) * BUFB;
    const char* lb = la + ABYTES;
    FragU fa[MR], fb[4];
    if (t + 3 < NT) STAGE_A(t + 3);
#pragma unroll
    for (int mf = 0; mf < MH; ++mf) fa[mf].s = *(const s16x8*)(la + ra[mf]);
#pragma unroll
    for (int nf = 0; nf < 4; ++nf) fb[nf].s = *(const s16x8*)(lb + rb[nf]);
    __builtin_amdgcn_s_barrier();
    asm volatile("s_waitcnt lgkmcnt(0)" ::: "memory");
    SB;
    __builtin_amdgcn_s_setprio(1);
#pragma unroll
    for (int mf = 0; mf < MH; ++mf)
#pragma unroll
      for (int nf = 0; nf < 4; ++nf)
        acc[mf][nf] = __builtin_amdgcn_mfma_f32_16x16x32_bf16(
            fa[mf].b, fb[nf].b, acc[mf][nf], 0, 0, 0);
    __builtin_amdgcn_s_setprio(0);
    __builtin_amdgcn_s_barrier();
    if (t + 3 < NT) STAGE_B(t + 3);
#pragma unroll
    for (int mf = MH; mf < MR; ++mf) fa[mf].s = *(const s16x8*)(la + ra[mf]);
    __builtin_amdgcn_s_barrier();
    asm volatile("s_waitcnt lgkmcnt(0)" ::: "memory");
    SB;
    __builtin_amdgcn_s_setprio(1);
#pragma unroll
    for (int mf = MH; mf < MR; ++mf)
#pragma unroll
      for (int nf = 0; nf < 4; ++nf)
        acc[mf][nf] = __builtin_amdgcn_mfma_f32_16x16x32_bf16(
            fa[mf].b, fb[nf].b, acc[mf][nf], 0, 0, 0);
    __builtin_amdgcn_s_setprio(0);
    if (t + 3 < NT) {
      waitcnt_vm<2 * LPT>();
    } else if (t + 2 < NT) {
      waitcnt_vm<LPT>();
    } else if (t + 1 < NT) {
      waitcnt_vm<0>();
    } else {
      break;
    }
    SB; __builtin_amdgcn_s_barrier(); SB;
  }
#undef STAGE_A
#undef STAGE_B

  const int rbase = (lane >> 4) * 4, cbase = lane & 15;
#pragma unroll
  for (int mf = 0; mf < MR; ++mf) {
#pragma unroll
    for (int nf = 0; nf < 4; ++nf) {
      const int gcol = n0 + wn * 64 + nf * 16 + cbase;
      float bn = (BIASMODE == 1) ? bias[gcol] : 0.f;
#pragma unroll
      for (int r = 0; r < 4; ++r) {
        const int grow = m0 + wm * (MR * 16) + mf * 16 + rbase + r;
        const size_t idx = (size_t)zb * sC + (size_t)grow * ldc + gcol;
        float v = acc[mf][nf][r];
        if constexpr (BIASMODE == 2) v += bias[grow]; else v += bn;
        if constexpr (OUTMODE == 0) {
          ((short*)Cptr)[idx] = f2bs(v);
        } else if constexpr (OUTMODE == 1) {
          __builtin_nontemporal_store(v, &((float*)Cptr)[idx]);
        } else if constexpr (OUTMODE == 2) {
          float p = 1.0f / (1.0f + __expf(-v * scale));
          __builtin_nontemporal_store(p, &((float*)Cptr)[idx]);
        } else {
          float p = 1.0f / (1.0f + __expf(-v * scale));
          __builtin_nontemporal_store(p, &((float*)Cptr)[idx]);
          C2p[idx] = f2bs(p);
        }
      }
    }
  }
}

// ---------------------------------------------------------------------------
// Fallback (tierB only): gload-staged 128x128 BK=64 GEMM, AF32 supported.
// ---------------------------------------------------------------------------
template <int OUTMODE, int BIASMODE, int AF32>
__global__ __launch_bounds__(256) void gemm_bt(
    const void* __restrict__ Aptr, const short* __restrict__ Btp,
    const float* __restrict__ bias, void* __restrict__ Cptr,
    short* __restrict__ C2p,
    int K, int lda, int ldb, int ldc,
    long long sA, long long sB, long long sC, float scale) {
  __shared__ __align__(16) short lsA[128 * 64];
  __shared__ __align__(16) short lsB[128 * 64];
  const int tid = threadIdx.x;
  const int lane = tid & 63, wid = tid >> 6;
  const int zb = blockIdx.z;
  const int m0 = blockIdx.y * 128, n0 = blockIdx.x * 128;
  const short* Ab = AF32 ? nullptr : (const short*)Aptr + (size_t)zb * sA;
  const float* Af = AF32 ? (const float*)Aptr + (size_t)zb * sA : nullptr;
  const short* Bt = Btp + (size_t)zb * sB;

  f32x4 acc[4][4] = {};
  const int woffM = (wid >> 1) * 64, woffN = (wid & 1) * 64;
  const int frow = lane & 15, fkg = lane >> 4;

  for (int k0 = 0; k0 < K; k0 += 64) {
    if (k0) __syncthreads();
    if constexpr (!AF32) {
#pragma unroll
      for (int i = 0; i < 4; ++i) {
        const int f = i * 4096 + tid * 16;
        const int row = f >> 7, colb = f & 127;
        gload16((const char*)Ab + ((size_t)(m0 + row) * lda + k0) * 2 + colb,
                (char*)lsA + f);
      }
    } else {
#pragma unroll
      for (int i = 0; i < 8; ++i) {
        int f = tid + i * 256;
        int row = f >> 4, c4 = f & 15;
        f32x4 v = *(const f32x4*)&Af[(size_t)(m0 + row) * lda + k0 + c4 * 4];
        union { short s[4]; unsigned long long q; } cv;
#pragma unroll
        for (int j = 0; j < 4; ++j) cv.s[j] = f2bs(v[j]);
        *(unsigned long long*)&lsA[row * 64 + c4 * 4] = cv.q;
      }
    }
#pragma unroll
    for (int i = 0; i < 4; ++i) {
      const int f = i * 4096 + tid * 16;
      const int row = f >> 7, colb = f & 127;
      gload16((const char*)Bt + ((size_t)(n0 + row) * ldb + k0) * 2 + colb,
              (char*)lsB + f);
    }
    __syncthreads();
#pragma unroll
    for (int kk = 0; kk < 2; ++kk) {
      const int kb = kk * 32 + fkg * 8;
      FragU fa[4], fb[4];
#pragma unroll
      for (int mf = 0; mf < 4; ++mf)
        fa[mf].s = *(const s16x8*)&lsA[(woffM + mf * 16 + frow) * 64 + kb];
#pragma unroll
      for (int nf = 0; nf < 4; ++nf)
        fb[nf].s = *(const s16x8*)&lsB[(woffN + nf * 16 + frow) * 64 + kb];
#pragma unroll
      for (int mf = 0; mf < 4; ++mf)
#pragma unroll
        for (int nf = 0; nf < 4; ++nf)
          acc[mf][nf] = __builtin_amdgcn_mfma_f32_16x16x32_bf16(
              fa[mf].b, fb[nf].b, acc[mf][nf], 0, 0, 0);
    }
  }

  const int rbase = (lane >> 4) * 4, cbase = lane & 15;
#pragma unroll
  for (int mf = 0; mf < 4; ++mf) {
#pragma unroll
    for (int nf = 0; nf < 4; ++nf) {
      const int gcol = n0 + woffN + nf * 16 + cbase;
      float bn = (BIASMODE == 1) ? bias[gcol] : 0.f;
#pragma unroll
      for (int r = 0; r < 4; ++r) {
        const int grow = m0 + woffM + mf * 16 + rbase + r;
        const size_t idx = (size_t)zb * sC + (size_t)grow * ldc + gcol;
        float v = acc[mf][nf][r];
        if constexpr (BIASMODE == 2) v += bias[grow]; else v += bn;
        if constexpr (OUTMODE == 0) {
          ((short*)Cptr)[idx] = f2bs(v);
        } else if constexpr (OUTMODE == 1) {
          ((float*)Cptr)[idx] = v;
        } else if constexpr (OUTMODE == 2) {
          ((float*)Cptr)[idx] = 1.0f / (1.0f + __expf(-v * scale));
        } else {
          float p = 1.0f / (1.0f + __expf(-v * scale));
          ((float*)Cptr)[idx] = p;
          C2p[idx] = f2bs(p);
        }
      }
    }
  }
}

extern "C" void kernel_launch(void* const* d_in, const int* in_sizes, int n_in,
                              void* d_out, int out_size, void* d_ws, size_t ws_size,
                              hipStream_t stream) {
  const float* in1 = (const float*)d_in[0];   // [16][512][2048]
  const float* in2 = (const float*)d_in[1];   // [16][768][1024]
  const float* Wq1 = (const float*)d_in[2];  const float* bq1 = (const float*)d_in[3];
  const float* Wk1 = (const float*)d_in[4];  const float* bk1 = (const float*)d_in[5];
  const float* Wv1 = (const float*)d_in[6];  const float* bv1 = (const float*)d_in[7];
  const float* Wq2 = (const float*)d_in[8];  const float* bq2 = (const float*)d_in[9];
  const float* Wk2 = (const float*)d_in[10]; const float* bk2 = (const float*)d_in[11];
  const float* Wv2 = (const float*)d_in[12]; const float* bv2 = (const float*)d_in[13];

  float* out = (float*)d_out;
  float* ctx2   = out;                                      // [16][2048][512]
  float* probs2 = out + (size_t)16 * 2048 * 512;            // [16][2048][1024]
  float* ctx1   = probs2 + (size_t)16 * 2048 * 1024;        // [16][1024][512]
  float* probs1 = ctx1 + (size_t)16 * 1024 * 512;           // [16][1024][2048]

  char* ws = (char*)d_ws;
  constexpr size_t O_WQ1T = 0;
  constexpr size_t O_WK1T = O_WQ1T + (size_t)512 * 512 * 2;
  constexpr size_t O_WV1T = O_WK1T + (size_t)512 * 512 * 2;
  constexpr size_t O_WQ2T = O_WV1T + (size_t)512 * 512 * 2;
  constexpr size_t O_WK2T = O_WQ2T + (size_t)768 * 512 * 2;
  constexpr size_t O_WV2T = O_WK2T + (size_t)768 * 512 * 2;
  constexpr size_t O_B1   = O_WV2T + (size_t)768 * 512 * 2;
  constexpr size_t O_B2   = O_B1 + 4096;
  constexpr size_t O_QK1  = O_B2 + 4096;                          // [32768][1024]
  constexpr size_t O_V1T  = O_QK1 + (size_t)32768 * 1024 * 2;     // [16][512][2048]
  constexpr size_t O_QK2  = O_V1T + (size_t)16 * 512 * 2048 * 2;  // [16384][1024]
  constexpr size_t O_V2T  = O_QK2 + (size_t)16384 * 1024 * 2;     // [16][512][1024]
  constexpr size_t O_X1B  = O_V2T + (size_t)16 * 512 * 1024 * 2;  // [32768][512]
  constexpr size_t O_X2B  = O_X1B + (size_t)32768 * 512 * 2;      // [16384][768]
  constexpr size_t O_PB1  = O_X2B + (size_t)16384 * 768 * 2;      // bf16 probs1
  constexpr size_t O_PB2  = O_PB1 + (size_t)16 * 1024 * 2048 * 2; // bf16 probs2
  constexpr size_t NEED_A = O_PB2 + (size_t)16 * 2048 * 1024 * 2;
  constexpr size_t NEED_B = O_PB1;

  short* wq1t = (short*)(ws + O_WQ1T);
  short* wk1t = (short*)(ws + O_WK1T);
  short* wv1t = (short*)(ws + O_WV1T);
  short* wq2t = (short*)(ws + O_WQ2T);
  short* wk2t = (short*)(ws + O_WK2T);
  short* wv2t = (short*)(ws + O_WV2T);
  float* b1c  = (float*)(ws + O_B1);
  float* b2c  = (float*)(ws + O_B2);
  short* qk1  = (short*)(ws + O_QK1);
  short* v1t  = (short*)(ws + O_V1T);
  short* qk2  = (short*)(ws + O_QK2);
  short* v2t  = (short*)(ws + O_V2T);
  short* x1b  = (short*)(ws + O_X1B);
  short* x2b  = (short*)(ws + O_X2B);
  short* pb1  = (short*)(ws + O_PB1);
  short* pb2  = (short*)(ws + O_PB2);

  const bool tierA = ws_size >= NEED_A;
  const bool tierB = ws_size >= NEED_B;
  if (!tierB) { x1b = (short*)probs1; x2b = (short*)probs2; }

  dim3 blk256(256), blk512(512);
  dim3 blkT(32, 8);

  // ---- stage 0 ----
  transpose_cvt<<<dim3(64, 8, 16), blkT, 0, stream>>>(in1, x1b, 512, 2048);
  transpose_cvt<<<dim3(32, 12, 16), blkT, 0, stream>>>(in2, x2b, 768, 1024);
  prep_weights<<<dim3(16, 12, 7), blkT, 0, stream>>>(
      Wq1, Wk1, Wv1, Wq2, Wk2, Wv2, wq1t, wk1t, wv1t, wq2t, wk2t, wv2t,
      bq1, bk1, bq2, bk2, b1c, b2c);

  const float scale = 0.04419417382415922f;  // 1/sqrt(512)
  const short* q1p = qk1;        // lda 1024
  const short* k1p = qk1 + 512;
  const short* q2p = qk2;
  const short* k2p = qk2 + 512;

  if (tierA) {
    // ---- P12: quad GEMM (qk1 | qk2 | v1t | v2t), one launch ----
    GArg a0{x1b, wq1t, b1c, qk1, 512, 512, 512, 1024,
            0, 0, 0, 4u, 128u, 512u, 1};
    GArg a1{x2b, wq2t, b2c, qk2, 768, 768, 768, 1024,
            0, 0, 0, 4u, 64u, 256u, 1};
    GArg a2{wv1t, x1b, bv1, v1t, 512, 512, 512, 2048,
            0, (long long)2048 * 512, (long long)512 * 2048, 8u, 2u, 256u, 2};
    GArg a3{wv2t, x2b, bv2, v2t, 768, 768, 768, 1024,
            0, (long long)1024 * 768, (long long)512 * 1024, 4u, 2u, 128u, 2};
    gemm8q<<<dim3(1152), blk512, 0, stream>>>(a0, a1, a2, a3);
    // ---- P3: scores1 + scores2 (sigmoid, dual store f32 nt + bf16) ----
    gemm8d<3, 0, 8><<<dim3(1024), blk512, 0, stream>>>(
        q2p, k1p, nullptr, probs1, pb1, 512, 1024, 1024, 2048,
        (long long)1024 * 1024, (long long)2048 * 1024, (long long)1024 * 2048,
        8u, 4u, 512u,
        q1p, k2p, nullptr, probs2, pb2, 512, 1024, 1024, 1024,
        (long long)2048 * 1024, (long long)1024 * 1024, (long long)2048 * 1024,
        4u, 8u, scale);
    // ---- P4: ctx1 + ctx2 (MR=4) ----
    gemm8d<1, 0, 4><<<dim3(768), blk512, 0, stream>>>(
        pb1, v1t, nullptr, ctx1, nullptr, 2048, 2048, 2048, 512,
        (long long)1024 * 2048, (long long)512 * 2048, (long long)1024 * 512,
        2u, 8u, 256u,
        pb2, v2t, nullptr, ctx2, nullptr, 1024, 1024, 1024, 512,
        (long long)2048 * 1024, (long long)512 * 1024, (long long)2048 * 512,
        2u, 16u, 1.f);
  } else {
    gemm_bt<0, 1, 0><<<dim3(8, 256, 1), blk256, 0, stream>>>(
        x1b, wq1t, b1c, qk1, nullptr, 512, 512, 512, 1024, 0, 0, 0, 1.f);
    gemm_bt<0, 1, 0><<<dim3(8, 128, 1), blk256, 0, stream>>>(
        x2b, wq2t, b2c, qk2, nullptr, 768, 768, 768, 1024, 0, 0, 0, 1.f);
    gemm_bt<0, 2, 0><<<dim3(16, 4, 16), blk256, 0, stream>>>(
        wv1t, x1b, bv1, v1t, nullptr, 512, 512, 512, 2048,
        0, (long long)2048 * 512, (long long)512 * 2048, 1.f);
    gemm_bt<0, 2, 0><<<dim3(8, 4, 16), blk256, 0, stream>>>(
        wv2t, x2b, bv2, v2t, nullptr, 768, 768, 768, 1024,
        0, (long long)1024 * 768, (long long)512 * 1024, 1.f);
    gemm_bt<2, 0, 0><<<dim3(16, 8, 16), blk256, 0, stream>>>(
        q2p, k1p, nullptr, probs1, nullptr, 512, 1024, 1024, 2048,
        (long long)1024 * 1024, (long long)2048 * 1024, (long long)1024 * 2048, scale);
    gemm_bt<2, 0, 0><<<dim3(8, 16, 16), blk256, 0, stream>>>(
        q1p, k2p, nullptr, probs2, nullptr, 512, 1024, 1024, 1024,
        (long long)2048 * 1024, (long long)1024 * 1024, (long long)2048 * 1024, scale);
    gemm_bt<1, 0, 1><<<dim3(4, 8, 16), blk256, 0, stream>>>(
        probs1, v1t, nullptr, ctx1, nullptr, 2048, 2048, 2048, 512,
        (long long)1024 * 2048, (long long)512 * 2048, (long long)1024 * 512, 1.f);
    gemm_bt<1, 0, 1><<<dim3(4, 16, 16), blk256, 0, stream>>>(
        probs2, v2t, nullptr, ctx2, nullptr, 1024, 1024, 1024, 512,
        (long long)2048 * 1024, (long long)512 * 1024, (long long)2048 * 512, 1.f);
  }
}

// Round 12
// 432.483 us; speedup vs baseline: 1.1450x; 1.0874x over previous
//
#include <hip/hip_runtime.h>
#include <hip/hip_bf16.h>

#define DEVFN __device__ __forceinline__
#define SB __builtin_amdgcn_sched_barrier(0)

typedef __attribute__((ext_vector_type(4))) float f32x4;
typedef __attribute__((ext_vector_type(8))) short s16x8;
typedef __attribute__((ext_vector_type(2))) short s16x2;
typedef __attribute__((ext_vector_type(8))) __bf16 bf16x8;

union FragU { s16x8 s; bf16x8 b; };

DEVFN short f2bs(float x) {
  union { __hip_bfloat16 h; short s; } u;
  u.h = __float2bfloat16(x);
  return u.s;
}

DEVFN void gload16(const void* g, void* l) {
  __builtin_amdgcn_global_load_lds(
      (const __attribute__((address_space(1))) void*)g,
      (__attribute__((address_space(3))) void*)l, 16, 0, 0);
}

template <int N> DEVFN void waitcnt_vm() {
  if constexpr (N == 0) asm volatile("s_waitcnt vmcnt(0)" ::: "memory");
  else if constexpr (N == 2) asm volatile("s_waitcnt vmcnt(2)" ::: "memory");
  else if constexpr (N == 3) asm volatile("s_waitcnt vmcnt(3)" ::: "memory");
  else if constexpr (N == 4) asm volatile("s_waitcnt vmcnt(4)" ::: "memory");
  else if constexpr (N == 6) asm volatile("s_waitcnt vmcnt(6)" ::: "memory");
  else if constexpr (N == 8) asm volatile("s_waitcnt vmcnt(8)" ::: "memory");
  else static_assert(N == 0, "unsupported vmcnt");
}

// ---------------------------------------------------------------------------
// Fused stage 0: both activation transposes + all weight transposes + bias
// concats in ONE launch (flat grid, block (32,8)).
//   blocks [0, 8192):          in1 [16][512][2048] -> x1b [16][2048][512]
//   blocks [8192, 14336):      in2 [16][768][1024] -> x2b [16][1024][768]
//   blocks [14336, 15680):     six weight transposes + bias concat
// ---------------------------------------------------------------------------
DEVFN void tr_tile(const float* __restrict__ in, short* __restrict__ out,
                   int C, int L, int l0, int c0, size_t base,
                   float (*tile)[33], int tx, int ty) {
#pragma unroll
  for (int i = ty; i < 64; i += 8)
    tile[i][tx] = in[base + (size_t)(c0 + i) * L + l0 + tx];
  __syncthreads();
#pragma unroll
  for (int i = ty; i < 32; i += 8) {
    s16x2 v;
    v[0] = f2bs(tile[2 * tx][i]);
    v[1] = f2bs(tile[2 * tx + 1][i]);
    *(s16x2*)&out[base + (size_t)(l0 + i) * C + c0 + 2 * tx] = v;
  }
}

__global__ __launch_bounds__(256) void stage0(
    const float* __restrict__ in1, const float* __restrict__ in2,
    short* x1b, short* x2b,
    const float* __restrict__ Wq1, const float* __restrict__ Wk1,
    const float* __restrict__ Wv1, const float* __restrict__ Wq2,
    const float* __restrict__ Wk2, const float* __restrict__ Wv2,
    short* wq1t, short* wk1t, short* wv1t,
    short* wq2t, short* wk2t, short* wv2t,
    const float* __restrict__ bq1, const float* __restrict__ bk1,
    const float* __restrict__ bq2, const float* __restrict__ bk2,
    float* b1c, float* b2c) {
  __shared__ float tile[64][33];
  const int tx = threadIdx.x, ty = threadIdx.y;
  const unsigned b = blockIdx.x;
  if (b < 8192u) {             // in1: x=b%64 (l), y=(b/64)%8 (c), z=b/512
    const int x = b & 63, y = (b >> 6) & 7, z = b >> 9;
    tr_tile(in1, x1b, 512, 2048, x * 32, y * 64,
            (size_t)z * 512 * 2048, tile, tx, ty);
    return;
  }
  if (b < 14336u) {            // in2: 6144 blocks: x%32, (b/32)%12, /384
    const unsigned bb = b - 8192u;
    const int x = bb & 31, y = (bb >> 5) % 12, z = bb / 384;
    tr_tile(in2, x2b, 768, 1024, x * 32, y * 64,
            (size_t)z * 768 * 1024, tile, tx, ty);
    return;
  }
  // weights/bias: 1344 blocks: x=bb%16, y=(bb/16)%12, z=bb/192 in 0..6
  const unsigned bb = b - 14336u;
  const int x = bb & 15, y = (bb >> 4) % 12, z = bb / 192;
  if (z == 6) {
    if (y != 0 || x >= 8) return;
    const int tid = ty * 32 + tx;
    const int i = (x & 3) * 256 + tid;
    const float* s = (x < 4) ? ((i < 512) ? bq1 : bk1)
                             : ((i < 512) ? bq2 : bk2);
    float* d = (x < 4) ? b1c : b2c;
    d[i] = s[i & 511];
    return;
  }
  const float* W; short* O; int C;
  switch (z) {
    case 0: W = Wq1; O = wq1t; C = 512; break;
    case 1: W = Wk1; O = wk1t; C = 512; break;
    case 2: W = Wv1; O = wv1t; C = 512; break;
    case 3: W = Wq2; O = wq2t; C = 768; break;
    case 4: W = Wk2; O = wk2t; C = 768; break;
    default: W = Wv2; O = wv2t; C = 768; break;
  }
  if (y * 64 >= C) return;
  tr_tile(W, O, C, 512, x * 32, y * 64, 0, tile, tx, ty);
}

// ---------------------------------------------------------------------------
// Dual-GEMM launch (R8-verified): deep-pipelined 256xBN (BM = MR*32).
// 8 waves (2M x 4N); acc[MR][4]; BK=32; 4 LDS bufs; depth-3 prefetch;
// counted vmcnt (never 0 until tail); 2-phase K-step; setprio on MFMA.
// Block split: h < nb0 -> GEMM 0 else GEMM 1; per-half bijective XCD remap.
// LDS layout: byte(r,cb) = (r>>1)*128 + (r&1)*64 + (cb ^ (((r>>1)&3)<<4)),
// linear gload dest + inverse-permuted per-lane global source.
// OUTMODE: 0=bf16, 1=f32(nt), 2=sigmoid f32(nt), 3=sigmoid f32(nt)+bf16 D
// BIASMODE: 0 none, 1 per-n, 2 per-m.  Requires NT = K/32 >= 3.
// ---------------------------------------------------------------------------
template <int OUTMODE, int BIASMODE, int MR>
__global__ __launch_bounds__(512, 2) void gemm8d(
    const short* __restrict__ A0, const short* __restrict__ B0,
    const float* __restrict__ bias0, void* __restrict__ C0, short* __restrict__ D0,
    int K0, int lda0, int ldb0, int ldc0,
    long long sA0, long long sB0, long long sC0,
    unsigned gx0, unsigned gy0, unsigned nb0,
    const short* __restrict__ A1, const short* __restrict__ B1,
    const float* __restrict__ bias1, void* __restrict__ C1, short* __restrict__ D1,
    int K1, int lda1, int ldb1, int ldc1,
    long long sA1, long long sB1, long long sC1,
    unsigned gx1, unsigned gy1, float scale) {
  constexpr int BM = MR * 32;
  constexpr int BN = 256;
  constexpr int LA = BM / 128;
  constexpr int LB = BN / 128;
  constexpr int LPT = LA + LB;
  constexpr int ABYTES = BM * 64;
  constexpr int BUFB = (BM + BN) * 64;
  constexpr int MH = MR / 2;
  __shared__ __align__(16) char smem[4 * BUFB];
  const int tid = threadIdx.x;
  const int lane = tid & 63, wid = tid >> 6;
  const int wm = wid >> 2, wn = wid & 3;

  const unsigned h = blockIdx.x;
  const bool sec = h >= nb0;
  const unsigned hh = sec ? h - nb0 : h;
  const unsigned nb = sec ? gridDim.x - nb0 : nb0;
  const unsigned gx = sec ? gx1 : gx0;
  const unsigned gy = sec ? gy1 : gy0;
  const short* Ap = sec ? A1 : A0;
  const short* Btp = sec ? B1 : B0;
  const float* bias = sec ? bias1 : bias0;
  void* Cptr = sec ? C1 : C0;
  short* C2p = sec ? D1 : D0;
  const int K = sec ? K1 : K0;
  const int lda = sec ? lda1 : lda0;
  const int ldb = sec ? ldb1 : ldb0;
  const int ldc = sec ? ldc1 : ldc0;
  const long long sA = sec ? sA1 : sA0;
  const long long sB = sec ? sB1 : sB0;
  const long long sC = sec ? sC1 : sC0;

  unsigned l = ((nb & 7u) == 0u) ? (hh & 7u) * (nb >> 3) + (hh >> 3) : hh;
  const unsigned bx = l % gx;
  const unsigned rem = l / gx;
  const unsigned by = rem % gy;
  const unsigned bz = rem / gy;

  const int zb = bz;
  const int m0 = by * BM, n0 = bx * BN;
  const char* Ab = (const char*)(Ap + (size_t)zb * sA);
  const char* Bb = (const char*)(Btp + (size_t)zb * sB);
  const size_t lda2 = (size_t)lda * 2, ldb2 = (size_t)ldb * 2;

  int s_r[2], s_cb[2];
#pragma unroll
  for (int j = 0; j < 2; ++j) {
    const int d = j * 8192 + tid * 16;
    const int line = d >> 7;
    s_r[j] = line * 2 + ((d >> 6) & 1);
    s_cb[j] = (d & 63) ^ ((line & 3) << 4);
  }

  f32x4 acc[MR][4] = {};
  const int frow = lane & 15, fkg = lane >> 4;

  int ra[MR], rb[4];
#pragma unroll
  for (int mf = 0; mf < MR; ++mf) {
    const int R = wm * (MR * 16) + mf * 16 + frow;
    ra[mf] = (R >> 1) * 128 + (R & 1) * 64 + ((fkg * 16) ^ (((R >> 1) & 3) << 4));
  }
#pragma unroll
  for (int nf = 0; nf < 4; ++nf) {
    const int R = wn * 64 + nf * 16 + frow;
    rb[nf] = (R >> 1) * 128 + (R & 1) * 64 + ((fkg * 16) ^ (((R >> 1) & 3) << 4));
  }

  const int NT = K >> 5;

#define STAGE_A(t)                                                       \
  {                                                                      \
    char* base_ = smem + ((t) & 3) * BUFB;                               \
    const size_t kb_ = (size_t)(t) * 64;                                 \
    _Pragma("unroll")                                                    \
    for (int j = 0; j < LA; ++j)                                         \
      gload16(Ab + (size_t)(m0 + s_r[j]) * lda2 + kb_ + s_cb[j],         \
              base_ + j * 8192 + tid * 16);                              \
  }
#define STAGE_B(t)                                                       \
  {                                                                      \
    char* base_ = smem + ((t) & 3) * BUFB + ABYTES;                      \
    const size_t kb_ = (size_t)(t) * 64;                                 \
    _Pragma("unroll")                                                    \
    for (int j = 0; j < LB; ++j)                                         \
      gload16(Bb + (size_t)(n0 + s_r[j]) * ldb2 + kb_ + s_cb[j],         \
              base_ + j * 8192 + tid * 16);                              \
  }

  STAGE_A(0); STAGE_B(0);
  STAGE_A(1); STAGE_B(1);
  STAGE_A(2); STAGE_B(2);
  waitcnt_vm<2 * LPT>();
  SB; __builtin_amdgcn_s_barrier(); SB;

  for (int t = 0; t < NT; ++t) {
    const char* la = smem + (t & 3) * BUFB;
    const char* lb = la + ABYTES;
    FragU fa[MR], fb[4];
    if (t + 3 < NT) STAGE_A(t + 3);
#pragma unroll
    for (int mf = 0; mf < MH; ++mf) fa[mf].s = *(const s16x8*)(la + ra[mf]);
#pragma unroll
    for (int nf = 0; nf < 4; ++nf) fb[nf].s = *(const s16x8*)(lb + rb[nf]);
    __builtin_amdgcn_s_barrier();
    asm volatile("s_waitcnt lgkmcnt(0)" ::: "memory");
    SB;
    __builtin_amdgcn_s_setprio(1);
#pragma unroll
    for (int mf = 0; mf < MH; ++mf)
#pragma unroll
      for (int nf = 0; nf < 4; ++nf)
        acc[mf][nf] = __builtin_amdgcn_mfma_f32_16x16x32_bf16(
            fa[mf].b, fb[nf].b, acc[mf][nf], 0, 0, 0);
    __builtin_amdgcn_s_setprio(0);
    __builtin_amdgcn_s_barrier();
    if (t + 3 < NT) STAGE_B(t + 3);
#pragma unroll
    for (int mf = MH; mf < MR; ++mf) fa[mf].s = *(const s16x8*)(la + ra[mf]);
    __builtin_amdgcn_s_barrier();
    asm volatile("s_waitcnt lgkmcnt(0)" ::: "memory");
    SB;
    __builtin_amdgcn_s_setprio(1);
#pragma unroll
    for (int mf = MH; mf < MR; ++mf)
#pragma unroll
      for (int nf = 0; nf < 4; ++nf)
        acc[mf][nf] = __builtin_amdgcn_mfma_f32_16x16x32_bf16(
            fa[mf].b, fb[nf].b, acc[mf][nf], 0, 0, 0);
    __builtin_amdgcn_s_setprio(0);
    if (t + 3 < NT) {
      waitcnt_vm<2 * LPT>();
    } else if (t + 2 < NT) {
      waitcnt_vm<LPT>();
    } else if (t + 1 < NT) {
      waitcnt_vm<0>();
    } else {
      break;
    }
    SB; __builtin_amdgcn_s_barrier(); SB;
  }
#undef STAGE_A
#undef STAGE_B

  const int rbase = (lane >> 4) * 4, cbase = lane & 15;
#pragma unroll
  for (int mf = 0; mf < MR; ++mf) {
#pragma unroll
    for (int nf = 0; nf < 4; ++nf) {
      const int gcol = n0 + wn * 64 + nf * 16 + cbase;
      float bn = (BIASMODE == 1) ? bias[gcol] : 0.f;
#pragma unroll
      for (int r = 0; r < 4; ++r) {
        const int grow = m0 + wm * (MR * 16) + mf * 16 + rbase + r;
        const size_t idx = (size_t)zb * sC + (size_t)grow * ldc + gcol;
        float v = acc[mf][nf][r];
        if constexpr (BIASMODE == 2) v += bias[grow]; else v += bn;
        if constexpr (OUTMODE == 0) {
          ((short*)Cptr)[idx] = f2bs(v);
        } else if constexpr (OUTMODE == 1) {
          __builtin_nontemporal_store(v, &((float*)Cptr)[idx]);
        } else if constexpr (OUTMODE == 2) {
          float p = 1.0f / (1.0f + __expf(-v * scale));
          __builtin_nontemporal_store(p, &((float*)Cptr)[idx]);
        } else {
          float p = 1.0f / (1.0f + __expf(-v * scale));
          __builtin_nontemporal_store(p, &((float*)Cptr)[idx]);
          C2p[idx] = f2bs(p);
        }
      }
    }
  }
}

// ---------------------------------------------------------------------------
// Fallback (tierB only): gload-staged 128x128 BK=64 GEMM, AF32 supported.
// ---------------------------------------------------------------------------
template <int OUTMODE, int BIASMODE, int AF32>
__global__ __launch_bounds__(256) void gemm_bt(
    const void* __restrict__ Aptr, const short* __restrict__ Btp,
    const float* __restrict__ bias, void* __restrict__ Cptr,
    short* __restrict__ C2p,
    int K, int lda, int ldb, int ldc,
    long long sA, long long sB, long long sC, float scale) {
  __shared__ __align__(16) short lsA[128 * 64];
  __shared__ __align__(16) short lsB[128 * 64];
  const int tid = threadIdx.x;
  const int lane = tid & 63, wid = tid >> 6;
  const int zb = blockIdx.z;
  const int m0 = blockIdx.y * 128, n0 = blockIdx.x * 128;
  const short* Ab = AF32 ? nullptr : (const short*)Aptr + (size_t)zb * sA;
  const float* Af = AF32 ? (const float*)Aptr + (size_t)zb * sA : nullptr;
  const short* Bt = Btp + (size_t)zb * sB;

  f32x4 acc[4][4] = {};
  const int woffM = (wid >> 1) * 64, woffN = (wid & 1) * 64;
  const int frow = lane & 15, fkg = lane >> 4;

  for (int k0 = 0; k0 < K; k0 += 64) {
    if (k0) __syncthreads();
    if constexpr (!AF32) {
#pragma unroll
      for (int i = 0; i < 4; ++i) {
        const int f = i * 4096 + tid * 16;
        const int row = f >> 7, colb = f & 127;
        gload16((const char*)Ab + ((size_t)(m0 + row) * lda + k0) * 2 + colb,
                (char*)lsA + f);
      }
    } else {
#pragma unroll
      for (int i = 0; i < 8; ++i) {
        int f = tid + i * 256;
        int row = f >> 4, c4 = f & 15;
        f32x4 v = *(const f32x4*)&Af[(size_t)(m0 + row) * lda + k0 + c4 * 4];
        union { short s[4]; unsigned long long q; } cv;
#pragma unroll
        for (int j = 0; j < 4; ++j) cv.s[j] = f2bs(v[j]);
        *(unsigned long long*)&lsA[row * 64 + c4 * 4] = cv.q;
      }
    }
#pragma unroll
    for (int i = 0; i < 4; ++i) {
      const int f = i * 4096 + tid * 16;
      const int row = f >> 7, colb = f & 127;
      gload16((const char*)Bt + ((size_t)(n0 + row) * ldb + k0) * 2 + colb,
              (char*)lsB + f);
    }
    __syncthreads();
#pragma unroll
    for (int kk = 0; kk < 2; ++kk) {
      const int kb = kk * 32 + fkg * 8;
      FragU fa[4], fb[4];
#pragma unroll
      for (int mf = 0; mf < 4; ++mf)
        fa[mf].s = *(const s16x8*)&lsA[(woffM + mf * 16 + frow) * 64 + kb];
#pragma unroll
      for (int nf = 0; nf < 4; ++nf)
        fb[nf].s = *(const s16x8*)&lsB[(woffN + nf * 16 + frow) * 64 + kb];
#pragma unroll
      for (int mf = 0; mf < 4; ++mf)
#pragma unroll
        for (int nf = 0; nf < 4; ++nf)
          acc[mf][nf] = __builtin_amdgcn_mfma_f32_16x16x32_bf16(
              fa[mf].b, fb[nf].b, acc[mf][nf], 0, 0, 0);
    }
  }

  const int rbase = (lane >> 4) * 4, cbase = lane & 15;
#pragma unroll
  for (int mf = 0; mf < 4; ++mf) {
#pragma unroll
    for (int nf = 0; nf < 4; ++nf) {
      const int gcol = n0 + woffN + nf * 16 + cbase;
      float bn = (BIASMODE == 1) ? bias[gcol] : 0.f;
#pragma unroll
      for (int r = 0; r < 4; ++r) {
        const int grow = m0 + woffM + mf * 16 + rbase + r;
        const size_t idx = (size_t)zb * sC + (size_t)grow * ldc + gcol;
        float v = acc[mf][nf][r];
        if constexpr (BIASMODE == 2) v += bias[grow]; else v += bn;
        if constexpr (OUTMODE == 0) {
          ((short*)Cptr)[idx] = f2bs(v);
        } else if constexpr (OUTMODE == 1) {
          ((float*)Cptr)[idx] = v;
        } else if constexpr (OUTMODE == 2) {
          ((float*)Cptr)[idx] = 1.0f / (1.0f + __expf(-v * scale));
        } else {
          float p = 1.0f / (1.0f + __expf(-v * scale));
          ((float*)Cptr)[idx] = p;
          C2p[idx] = f2bs(p);
        }
      }
    }
  }
}

extern "C" void kernel_launch(void* const* d_in, const int* in_sizes, int n_in,
                              void* d_out, int out_size, void* d_ws, size_t ws_size,
                              hipStream_t stream) {
  const float* in1 = (const float*)d_in[0];   // [16][512][2048]
  const float* in2 = (const float*)d_in[1];   // [16][768][1024]
  const float* Wq1 = (const float*)d_in[2];  const float* bq1 = (const float*)d_in[3];
  const float* Wk1 = (const float*)d_in[4];  const float* bk1 = (const float*)d_in[5];
  const float* Wv1 = (const float*)d_in[6];  const float* bv1 = (const float*)d_in[7];
  const float* Wq2 = (const float*)d_in[8];  const float* bq2 = (const float*)d_in[9];
  const float* Wk2 = (const float*)d_in[10]; const float* bk2 = (const float*)d_in[11];
  const float* Wv2 = (const float*)d_in[12]; const float* bv2 = (const float*)d_in[13];

  float* out = (float*)d_out;
  float* ctx2   = out;                                      // [16][2048][512]
  float* probs2 = out + (size_t)16 * 2048 * 512;            // [16][2048][1024]
  float* ctx1   = probs2 + (size_t)16 * 2048 * 1024;        // [16][1024][512]
  float* probs1 = ctx1 + (size_t)16 * 1024 * 512;           // [16][1024][2048]

  char* ws = (char*)d_ws;
  constexpr size_t O_WQ1T = 0;
  constexpr size_t O_WK1T = O_WQ1T + (size_t)512 * 512 * 2;
  constexpr size_t O_WV1T = O_WK1T + (size_t)512 * 512 * 2;
  constexpr size_t O_WQ2T = O_WV1T + (size_t)512 * 512 * 2;
  constexpr size_t O_WK2T = O_WQ2T + (size_t)768 * 512 * 2;
  constexpr size_t O_WV2T = O_WK2T + (size_t)768 * 512 * 2;
  constexpr size_t O_B1   = O_WV2T + (size_t)768 * 512 * 2;
  constexpr size_t O_B2   = O_B1 + 4096;
  constexpr size_t O_QK1  = O_B2 + 4096;                          // [32768][1024]
  constexpr size_t O_V1T  = O_QK1 + (size_t)32768 * 1024 * 2;     // [16][512][2048]
  constexpr size_t O_QK2  = O_V1T + (size_t)16 * 512 * 2048 * 2;  // [16384][1024]
  constexpr size_t O_V2T  = O_QK2 + (size_t)16384 * 1024 * 2;     // [16][512][1024]
  constexpr size_t O_X1B  = O_V2T + (size_t)16 * 512 * 1024 * 2;  // [32768][512]
  constexpr size_t O_X2B  = O_X1B + (size_t)32768 * 512 * 2;      // [16384][768]
  constexpr size_t O_PB1  = O_X2B + (size_t)16384 * 768 * 2;      // bf16 probs1
  constexpr size_t O_PB2  = O_PB1 + (size_t)16 * 1024 * 2048 * 2; // bf16 probs2
  constexpr size_t NEED_A = O_PB2 + (size_t)16 * 2048 * 1024 * 2;
  constexpr size_t NEED_B = O_PB1;

  short* wq1t = (short*)(ws + O_WQ1T);
  short* wk1t = (short*)(ws + O_WK1T);
  short* wv1t = (short*)(ws + O_WV1T);
  short* wq2t = (short*)(ws + O_WQ2T);
  short* wk2t = (short*)(ws + O_WK2T);
  short* wv2t = (short*)(ws + O_WV2T);
  float* b1c  = (float*)(ws + O_B1);
  float* b2c  = (float*)(ws + O_B2);
  short* qk1  = (short*)(ws + O_QK1);
  short* v1t  = (short*)(ws + O_V1T);
  short* qk2  = (short*)(ws + O_QK2);
  short* v2t  = (short*)(ws + O_V2T);
  short* x1b  = (short*)(ws + O_X1B);
  short* x2b  = (short*)(ws + O_X2B);
  short* pb1  = (short*)(ws + O_PB1);
  short* pb2  = (short*)(ws + O_PB2);

  const bool tierA = ws_size >= NEED_A;
  const bool tierB = ws_size >= NEED_B;
  if (!tierB) { x1b = (short*)probs1; x2b = (short*)probs2; }

  dim3 blk256(256), blk512(512);
  dim3 blkT(32, 8);

  // ---- stage 0: one fused launch (15680 blocks) ----
  stage0<<<dim3(15680), blkT, 0, stream>>>(
      in1, in2, x1b, x2b, Wq1, Wk1, Wv1, Wq2, Wk2, Wv2,
      wq1t, wk1t, wv1t, wq2t, wk2t, wv2t,
      bq1, bk1, bq2, bk2, b1c, b2c);

  const float scale = 0.04419417382415922f;  // 1/sqrt(512)
  const short* q1p = qk1;        // lda 1024
  const short* k1p = qk1 + 512;
  const short* q2p = qk2;
  const short* k2p = qk2 + 512;

  if (tierA) {
    // ---- P1: qk1 + qk2 (one launch, 512+256 = 768 blocks) ----
    gemm8d<0, 1, 8><<<dim3(768), blk512, 0, stream>>>(
        x1b, wq1t, b1c, qk1, nullptr, 512, 512, 512, 1024, 0, 0, 0,
        4u, 128u, 512u,
        x2b, wq2t, b2c, qk2, nullptr, 768, 768, 768, 1024, 0, 0, 0,
        4u, 64u, 1.f);
    // ---- P2: v1t + v2t (MR=4; 512+256 = 768 blocks) ----
    gemm8d<0, 2, 4><<<dim3(768), blk512, 0, stream>>>(
        wv1t, x1b, bv1, v1t, nullptr, 512, 512, 512, 2048,
        0, (long long)2048 * 512, (long long)512 * 2048,
        8u, 4u, 512u,
        wv2t, x2b, bv2, v2t, nullptr, 768, 768, 768, 1024,
        0, (long long)1024 * 768, (long long)512 * 1024,
        4u, 4u, 1.f);
    // ---- P3: scores1 + scores2 (512+512 = 1024 blocks) ----
    gemm8d<3, 0, 8><<<dim3(1024), blk512, 0, stream>>>(
        q2p, k1p, nullptr, probs1, pb1, 512, 1024, 1024, 2048,
        (long long)1024 * 1024, (long long)2048 * 1024, (long long)1024 * 2048,
        8u, 4u, 512u,
        q1p, k2p, nullptr, probs2, pb2, 512, 1024, 1024, 1024,
        (long long)2048 * 1024, (long long)1024 * 1024, (long long)2048 * 1024,
        4u, 8u, scale);
    // ---- P4: ctx1 + ctx2 (MR=4; 256+512 = 768 blocks) ----
    gemm8d<1, 0, 4><<<dim3(768), blk512, 0, stream>>>(
        pb1, v1t, nullptr, ctx1, nullptr, 2048, 2048, 2048, 512,
        (long long)1024 * 2048, (long long)512 * 2048, (long long)1024 * 512,
        2u, 8u, 256u,
        pb2, v2t, nullptr, ctx2, nullptr, 1024, 1024, 1024, 512,
        (long long)2048 * 1024, (long long)512 * 1024, (long long)2048 * 512,
        2u, 16u, 1.f);
  } else {
    gemm_bt<0, 1, 0><<<dim3(8, 256, 1), blk256, 0, stream>>>(
        x1b, wq1t, b1c, qk1, nullptr, 512, 512, 512, 1024, 0, 0, 0, 1.f);
    gemm_bt<0, 1, 0><<<dim3(8, 128, 1), blk256, 0, stream>>>(
        x2b, wq2t, b2c, qk2, nullptr, 768, 768, 768, 1024, 0, 0, 0, 1.f);
    gemm_bt<0, 2, 0><<<dim3(16, 4, 16), blk256, 0, stream>>>(
        wv1t, x1b, bv1, v1t, nullptr, 512, 512, 512, 2048,
        0, (long long)2048 * 512, (long long)512 * 2048, 1.f);
    gemm_bt<0, 2, 0><<<dim3(8, 4, 16), blk256, 0, stream>>>(
        wv2t, x2b, bv2, v2t, nullptr, 768, 768, 768, 1024,
        0, (long long)1024 * 768, (long long)512 * 1024, 1.f);
    gemm_bt<2, 0, 0><<<dim3(16, 8, 16), blk256, 0, stream>>>(
        q2p, k1p, nullptr, probs1, nullptr, 512, 1024, 1024, 2048,
        (long long)1024 * 1024, (long long)2048 * 1024, (long long)1024 * 2048, scale);
    gemm_bt<2, 0, 0><<<dim3(8, 16, 16), blk256, 0, stream>>>(
        q1p, k2p, nullptr, probs2, nullptr, 512, 1024, 1024, 1024,
        (long long)2048 * 1024, (long long)1024 * 1024, (long long)2048 * 1024, scale);
    gemm_bt<1, 0, 1><<<dim3(4, 8, 16), blk256, 0, stream>>>(
        probs1, v1t, nullptr, ctx1, nullptr, 2048, 2048, 2048, 512,
        (long long)1024 * 2048, (long long)512 * 2048, (long long)1024 * 512, 1.f);
    gemm_bt<1, 0, 1><<<dim3(4, 16, 16), blk256, 0, stream>>>(
        probs2, v2t, nullptr, ctx2, nullptr, 1024, 1024, 1024, 512,
        (long long)2048 * 1024, (long long)512 * 1024, (long long)2048 * 512, 1.f);
  }
}

// Round 13
// 429.934 us; speedup vs baseline: 1.1518x; 1.0059x over previous
//
#include <hip/hip_runtime.h>
#include <hip/hip_bf16.h>

#define DEVFN __device__ __forceinline__
#define SB __builtin_amdgcn_sched_barrier(0)

typedef __attribute__((ext_vector_type(4))) float f32x4;
typedef __attribute__((ext_vector_type(8))) short s16x8;
typedef __attribute__((ext_vector_type(2))) short s16x2;
typedef __attribute__((ext_vector_type(8))) __bf16 bf16x8;

union FragU { s16x8 s; bf16x8 b; };

DEVFN short f2bs(float x) {
  union { __hip_bfloat16 h; short s; } u;
  u.h = __float2bfloat16(x);
  return u.s;
}

DEVFN void gload16(const void* g, void* l) {
  __builtin_amdgcn_global_load_lds(
      (const __attribute__((address_space(1))) void*)g,
      (__attribute__((address_space(3))) void*)l, 16, 0, 0);
}

template <int N> DEVFN void waitcnt_vm() {
  if constexpr (N == 0) asm volatile("s_waitcnt vmcnt(0)" ::: "memory");
  else if constexpr (N == 2) asm volatile("s_waitcnt vmcnt(2)" ::: "memory");
  else if constexpr (N == 3) asm volatile("s_waitcnt vmcnt(3)" ::: "memory");
  else if constexpr (N == 4) asm volatile("s_waitcnt vmcnt(4)" ::: "memory");
  else if constexpr (N == 6) asm volatile("s_waitcnt vmcnt(6)" ::: "memory");
  else if constexpr (N == 8) asm volatile("s_waitcnt vmcnt(8)" ::: "memory");
  else static_assert(N == 0, "unsupported vmcnt");
}

// ---------------------------------------------------------------------------
// Fused stage 0: both activation transposes + all weight transposes + bias
// concats in ONE launch (flat grid, block (32,8)).
// ---------------------------------------------------------------------------
DEVFN void tr_tile(const float* __restrict__ in, short* __restrict__ out,
                   int C, int L, int l0, int c0, size_t base,
                   float (*tile)[33], int tx, int ty) {
#pragma unroll
  for (int i = ty; i < 64; i += 8)
    tile[i][tx] = in[base + (size_t)(c0 + i) * L + l0 + tx];
  __syncthreads();
#pragma unroll
  for (int i = ty; i < 32; i += 8) {
    s16x2 v;
    v[0] = f2bs(tile[2 * tx][i]);
    v[1] = f2bs(tile[2 * tx + 1][i]);
    *(s16x2*)&out[base + (size_t)(l0 + i) * C + c0 + 2 * tx] = v;
  }
}

__global__ __launch_bounds__(256) void stage0(
    const float* __restrict__ in1, const float* __restrict__ in2,
    short* x1b, short* x2b,
    const float* __restrict__ Wq1, const float* __restrict__ Wk1,
    const float* __restrict__ Wv1, const float* __restrict__ Wq2,
    const float* __restrict__ Wk2, const float* __restrict__ Wv2,
    short* wq1t, short* wk1t, short* wv1t,
    short* wq2t, short* wk2t, short* wv2t,
    const float* __restrict__ bq1, const float* __restrict__ bk1,
    const float* __restrict__ bq2, const float* __restrict__ bk2,
    float* b1c, float* b2c) {
  __shared__ float tile[64][33];
  const int tx = threadIdx.x, ty = threadIdx.y;
  const unsigned b = blockIdx.x;
  if (b < 8192u) {
    const int x = b & 63, y = (b >> 6) & 7, z = b >> 9;
    tr_tile(in1, x1b, 512, 2048, x * 32, y * 64,
            (size_t)z * 512 * 2048, tile, tx, ty);
    return;
  }
  if (b < 14336u) {
    const unsigned bb = b - 8192u;
    const int x = bb & 31, y = (bb >> 5) % 12, z = bb / 384;
    tr_tile(in2, x2b, 768, 1024, x * 32, y * 64,
            (size_t)z * 768 * 1024, tile, tx, ty);
    return;
  }
  const unsigned bb = b - 14336u;
  const int x = bb & 15, y = (bb >> 4) % 12, z = bb / 192;
  if (z == 6) {
    if (y != 0 || x >= 8) return;
    const int tid = ty * 32 + tx;
    const int i = (x & 3) * 256 + tid;
    const float* s = (x < 4) ? ((i < 512) ? bq1 : bk1)
                             : ((i < 512) ? bq2 : bk2);
    float* d = (x < 4) ? b1c : b2c;
    d[i] = s[i & 511];
    return;
  }
  const float* W; short* O; int C;
  switch (z) {
    case 0: W = Wq1; O = wq1t; C = 512; break;
    case 1: W = Wk1; O = wk1t; C = 512; break;
    case 2: W = Wv1; O = wv1t; C = 512; break;
    case 3: W = Wq2; O = wq2t; C = 768; break;
    case 4: W = Wk2; O = wk2t; C = 768; break;
    default: W = Wv2; O = wv2t; C = 768; break;
  }
  if (y * 64 >= C) return;
  tr_tile(W, O, C, 512, x * 32, y * 64, 0, tile, tx, ty);
}

// ---------------------------------------------------------------------------
// Dual-GEMM launch: deep-pipelined 256xBN (BM = MR*32).
// DEPTH=3: 4 LDS bufs (1 block/CU at MR=8).  DEPTH=2: 3 bufs — at MR=4 this
// is 72 KB, and with MINW=4 (VGPR<=128) gives 2 blocks/CU (cross-block TLP).
// Counted vmcnt (never 0 until tail); 2-phase K-step; setprio on MFMA.
// Block split h<nb0 -> GEMM0 else GEMM1; per-half bijective XCD remap.
// OUTMODE: 0=bf16, 1=f32(nt), 2=sigmoid f32(nt), 3=sigmoid f32(nt)+bf16 D
// BIASMODE: 0 none, 1 per-n, 2 per-m.  Requires NT = K/32 >= DEPTH.
// ---------------------------------------------------------------------------
template <int OUTMODE, int BIASMODE, int MR, int DEPTH, int MINW>
__global__ __launch_bounds__(512, MINW) void gemm8d(
    const short* __restrict__ A0, const short* __restrict__ B0,
    const float* __restrict__ bias0, void* __restrict__ C0, short* __restrict__ D0,
    int K0, int lda0, int ldb0, int ldc0,
    long long sA0, long long sB0, long long sC0,
    unsigned gx0, unsigned gy0, unsigned nb0,
    const short* __restrict__ A1, const short* __restrict__ B1,
    const float* __restrict__ bias1, void* __restrict__ C1, short* __restrict__ D1,
    int K1, int lda1, int ldb1, int ldc1,
    long long sA1, long long sB1, long long sC1,
    unsigned gx1, unsigned gy1, float scale) {
  constexpr int BM = MR * 32;
  constexpr int BN = 256;
  constexpr int LA = BM / 128;
  constexpr int LB = BN / 128;
  constexpr int LPT = LA + LB;
  constexpr int ABYTES = BM * 64;
  constexpr int BUFB = (BM + BN) * 64;
  constexpr int NBUF = DEPTH + 1;
  constexpr int MH = MR / 2;
  __shared__ __align__(16) char smem[NBUF * BUFB];
  const int tid = threadIdx.x;
  const int lane = tid & 63, wid = tid >> 6;
  const int wm = wid >> 2, wn = wid & 3;

  const unsigned h = blockIdx.x;
  const bool sec = h >= nb0;
  const unsigned hh = sec ? h - nb0 : h;
  const unsigned nb = sec ? gridDim.x - nb0 : nb0;
  const unsigned gx = sec ? gx1 : gx0;
  const unsigned gy = sec ? gy1 : gy0;
  const short* Ap = sec ? A1 : A0;
  const short* Btp = sec ? B1 : B0;
  const float* bias = sec ? bias1 : bias0;
  void* Cptr = sec ? C1 : C0;
  short* C2p = sec ? D1 : D0;
  const int K = sec ? K1 : K0;
  const int lda = sec ? lda1 : lda0;
  const int ldb = sec ? ldb1 : ldb0;
  const int ldc = sec ? ldc1 : ldc0;
  const long long sA = sec ? sA1 : sA0;
  const long long sB = sec ? sB1 : sB0;
  const long long sC = sec ? sC1 : sC0;

  unsigned l = ((nb & 7u) == 0u) ? (hh & 7u) * (nb >> 3) + (hh >> 3) : hh;
  const unsigned bx = l % gx;
  const unsigned rem = l / gx;
  const unsigned by = rem % gy;
  const unsigned bz = rem / gy;

  const int zb = bz;
  const int m0 = by * BM, n0 = bx * BN;
  const char* Ab = (const char*)(Ap + (size_t)zb * sA);
  const char* Bb = (const char*)(Btp + (size_t)zb * sB);
  const size_t lda2 = (size_t)lda * 2, ldb2 = (size_t)ldb * 2;

  int s_r[2], s_cb[2];
#pragma unroll
  for (int j = 0; j < 2; ++j) {
    const int d = j * 8192 + tid * 16;
    const int line = d >> 7;
    s_r[j] = line * 2 + ((d >> 6) & 1);
    s_cb[j] = (d & 63) ^ ((line & 3) << 4);
  }

  f32x4 acc[MR][4] = {};
  const int frow = lane & 15, fkg = lane >> 4;

  int ra[MR], rb[4];
#pragma unroll
  for (int mf = 0; mf < MR; ++mf) {
    const int R = wm * (MR * 16) + mf * 16 + frow;
    ra[mf] = (R >> 1) * 128 + (R & 1) * 64 + ((fkg * 16) ^ (((R >> 1) & 3) << 4));
  }
#pragma unroll
  for (int nf = 0; nf < 4; ++nf) {
    const int R = wn * 64 + nf * 16 + frow;
    rb[nf] = (R >> 1) * 128 + (R & 1) * 64 + ((fkg * 16) ^ (((R >> 1) & 3) << 4));
  }

  const int NT = K >> 5;

#define STAGE_A(t)                                                       \
  {                                                                      \
    char* base_ = smem + ((t) % NBUF) * BUFB;                            \
    const size_t kb_ = (size_t)(t) * 64;                                 \
    _Pragma("unroll")                                                    \
    for (int j = 0; j < LA; ++j)                                         \
      gload16(Ab + (size_t)(m0 + s_r[j]) * lda2 + kb_ + s_cb[j],         \
              base_ + j * 8192 + tid * 16);                              \
  }
#define STAGE_B(t)                                                       \
  {                                                                      \
    char* base_ = smem + ((t) % NBUF) * BUFB + ABYTES;                   \
    const size_t kb_ = (size_t)(t) * 64;                                 \
    _Pragma("unroll")                                                    \
    for (int j = 0; j < LB; ++j)                                         \
      gload16(Bb + (size_t)(n0 + s_r[j]) * ldb2 + kb_ + s_cb[j],         \
              base_ + j * 8192 + tid * 16);                              \
  }

  STAGE_A(0); STAGE_B(0);
  STAGE_A(1); STAGE_B(1);
  if constexpr (DEPTH == 3) { STAGE_A(2); STAGE_B(2); }
  waitcnt_vm<(DEPTH - 1) * LPT>();
  SB; __builtin_amdgcn_s_barrier(); SB;

  for (int t = 0; t < NT; ++t) {
    const char* la = smem + (t % NBUF) * BUFB;
    const char* lb = la + ABYTES;
    FragU fa[MR], fb[4];
    if (t + DEPTH < NT) STAGE_A(t + DEPTH);
#pragma unroll
    for (int mf = 0; mf < MH; ++mf) fa[mf].s = *(const s16x8*)(la + ra[mf]);
#pragma unroll
    for (int nf = 0; nf < 4; ++nf) fb[nf].s = *(const s16x8*)(lb + rb[nf]);
    __builtin_amdgcn_s_barrier();
    asm volatile("s_waitcnt lgkmcnt(0)" ::: "memory");
    SB;
    __builtin_amdgcn_s_setprio(1);
#pragma unroll
    for (int mf = 0; mf < MH; ++mf)
#pragma unroll
      for (int nf = 0; nf < 4; ++nf)
        acc[mf][nf] = __builtin_amdgcn_mfma_f32_16x16x32_bf16(
            fa[mf].b, fb[nf].b, acc[mf][nf], 0, 0, 0);
    __builtin_amdgcn_s_setprio(0);
    __builtin_amdgcn_s_barrier();
    if (t + DEPTH < NT) STAGE_B(t + DEPTH);
#pragma unroll
    for (int mf = MH; mf < MR; ++mf) fa[mf].s = *(const s16x8*)(la + ra[mf]);
    __builtin_amdgcn_s_barrier();
    asm volatile("s_waitcnt lgkmcnt(0)" ::: "memory");
    SB;
    __builtin_amdgcn_s_setprio(1);
#pragma unroll
    for (int mf = MH; mf < MR; ++mf)
#pragma unroll
      for (int nf = 0; nf < 4; ++nf)
        acc[mf][nf] = __builtin_amdgcn_mfma_f32_16x16x32_bf16(
            fa[mf].b, fb[nf].b, acc[mf][nf], 0, 0, 0);
    __builtin_amdgcn_s_setprio(0);
    if constexpr (DEPTH == 3) {
      if (t + 3 < NT) {
        waitcnt_vm<2 * LPT>();
      } else if (t + 2 < NT) {
        waitcnt_vm<LPT>();
      } else if (t + 1 < NT) {
        waitcnt_vm<0>();
      } else {
        break;
      }
    } else {
      if (t + 2 < NT) {
        waitcnt_vm<LPT>();
      } else if (t + 1 < NT) {
        waitcnt_vm<0>();
      } else {
        break;
      }
    }
    SB; __builtin_amdgcn_s_barrier(); SB;
  }
#undef STAGE_A
#undef STAGE_B

  const int rbase = (lane >> 4) * 4, cbase = lane & 15;
#pragma unroll
  for (int mf = 0; mf < MR; ++mf) {
#pragma unroll
    for (int nf = 0; nf < 4; ++nf) {
      const int gcol = n0 + wn * 64 + nf * 16 + cbase;
      float bn = (BIASMODE == 1) ? bias[gcol] : 0.f;
#pragma unroll
      for (int r = 0; r < 4; ++r) {
        const int grow = m0 + wm * (MR * 16) + mf * 16 + rbase + r;
        const size_t idx = (size_t)zb * sC + (size_t)grow * ldc + gcol;
        float v = acc[mf][nf][r];
        if constexpr (BIASMODE == 2) v += bias[grow]; else v += bn;
        if constexpr (OUTMODE == 0) {
          ((short*)Cptr)[idx] = f2bs(v);
        } else if constexpr (OUTMODE == 1) {
          __builtin_nontemporal_store(v, &((float*)Cptr)[idx]);
        } else if constexpr (OUTMODE == 2) {
          float p = 1.0f / (1.0f + __expf(-v * scale));
          __builtin_nontemporal_store(p, &((float*)Cptr)[idx]);
        } else {
          float p = 1.0f / (1.0f + __expf(-v * scale));
          __builtin_nontemporal_store(p, &((float*)Cptr)[idx]);
          C2p[idx] = f2bs(p);
        }
      }
    }
  }
}

// ---------------------------------------------------------------------------
// Fallback (tierB only): gload-staged 128x128 BK=64 GEMM, AF32 supported.
// ---------------------------------------------------------------------------
template <int OUTMODE, int BIASMODE, int AF32>
__global__ __launch_bounds__(256) void gemm_bt(
    const void* __restrict__ Aptr, const short* __restrict__ Btp,
    const float* __restrict__ bias, void* __restrict__ Cptr,
    short* __restrict__ C2p,
    int K, int lda, int ldb, int ldc,
    long long sA, long long sB, long long sC, float scale) {
  __shared__ __align__(16) short lsA[128 * 64];
  __shared__ __align__(16) short lsB[128 * 64];
  const int tid = threadIdx.x;
  const int lane = tid & 63, wid = tid >> 6;
  const int zb = blockIdx.z;
  const int m0 = blockIdx.y * 128, n0 = blockIdx.x * 128;
  const short* Ab = AF32 ? nullptr : (const short*)Aptr + (size_t)zb * sA;
  const float* Af = AF32 ? (const float*)Aptr + (size_t)zb * sA : nullptr;
  const short* Bt = Btp + (size_t)zb * sB;

  f32x4 acc[4][4] = {};
  const int woffM = (wid >> 1) * 64, woffN = (wid & 1) * 64;
  const int frow = lane & 15, fkg = lane >> 4;

  for (int k0 = 0; k0 < K; k0 += 64) {
    if (k0) __syncthreads();
    if constexpr (!AF32) {
#pragma unroll
      for (int i = 0; i < 4; ++i) {
        const int f = i * 4096 + tid * 16;
        const int row = f >> 7, colb = f & 127;
        gload16((const char*)Ab + ((size_t)(m0 + row) * lda + k0) * 2 + colb,
                (char*)lsA + f);
      }
    } else {
#pragma unroll
      for (int i = 0; i < 8; ++i) {
        int f = tid + i * 256;
        int row = f >> 4, c4 = f & 15;
        f32x4 v = *(const f32x4*)&Af[(size_t)(m0 + row) * lda + k0 + c4 * 4];
        union { short s[4]; unsigned long long q; } cv;
#pragma unroll
        for (int j = 0; j < 4; ++j) cv.s[j] = f2bs(v[j]);
        *(unsigned long long*)&lsA[row * 64 + c4 * 4] = cv.q;
      }
    }
#pragma unroll
    for (int i = 0; i < 4; ++i) {
      const int f = i * 4096 + tid * 16;
      const int row = f >> 7, colb = f & 127;
      gload16((const char*)Bt + ((size_t)(n0 + row) * ldb + k0) * 2 + colb,
              (char*)lsB + f);
    }
    __syncthreads();
#pragma unroll
    for (int kk = 0; kk < 2; ++kk) {
      const int kb = kk * 32 + fkg * 8;
      FragU fa[4], fb[4];
#pragma unroll
      for (int mf = 0; mf < 4; ++mf)
        fa[mf].s = *(const s16x8*)&lsA[(woffM + mf * 16 + frow) * 64 + kb];
#pragma unroll
      for (int nf = 0; nf < 4; ++nf)
        fb[nf].s = *(const s16x8*)&lsB[(woffN + nf * 16 + frow) * 64 + kb];
#pragma unroll
      for (int mf = 0; mf < 4; ++mf)
#pragma unroll
        for (int nf = 0; nf < 4; ++nf)
          acc[mf][nf] = __builtin_amdgcn_mfma_f32_16x16x32_bf16(
              fa[mf].b, fb[nf].b, acc[mf][nf], 0, 0, 0);
    }
  }

  const int rbase = (lane >> 4) * 4, cbase = lane & 15;
#pragma unroll
  for (int mf = 0; mf < 4; ++mf) {
#pragma unroll
    for (int nf = 0; nf < 4; ++nf) {
      const int gcol = n0 + woffN + nf * 16 + cbase;
      float bn = (BIASMODE == 1) ? bias[gcol] : 0.f;
#pragma unroll
      for (int r = 0; r < 4; ++r) {
        const int grow = m0 + woffM + mf * 16 + rbase + r;
        const size_t idx = (size_t)zb * sC + (size_t)grow * ldc + gcol;
        float v = acc[mf][nf][r];
        if constexpr (BIASMODE == 2) v += bias[grow]; else v += bn;
        if constexpr (OUTMODE == 0) {
          ((short*)Cptr)[idx] = f2bs(v);
        } else if constexpr (OUTMODE == 1) {
          ((float*)Cptr)[idx] = v;
        } else if constexpr (OUTMODE == 2) {
          ((float*)Cptr)[idx] = 1.0f / (1.0f + __expf(-v * scale));
        } else {
          float p = 1.0f / (1.0f + __expf(-v * scale));
          ((float*)Cptr)[idx] = p;
          C2p[idx] = f2bs(p);
        }
      }
    }
  }
}

extern "C" void kernel_launch(void* const* d_in, const int* in_sizes, int n_in,
                              void* d_out, int out_size, void* d_ws, size_t ws_size,
                              hipStream_t stream) {
  const float* in1 = (const float*)d_in[0];   // [16][512][2048]
  const float* in2 = (const float*)d_in[1];   // [16][768][1024]
  const float* Wq1 = (const float*)d_in[2];  const float* bq1 = (const float*)d_in[3];
  const float* Wk1 = (const float*)d_in[4];  const float* bk1 = (const float*)d_in[5];
  const float* Wv1 = (const float*)d_in[6];  const float* bv1 = (const float*)d_in[7];
  const float* Wq2 = (const float*)d_in[8];  const float* bq2 = (const float*)d_in[9];
  const float* Wk2 = (const float*)d_in[10]; const float* bk2 = (const float*)d_in[11];
  const float* Wv2 = (const float*)d_in[12]; const float* bv2 = (const float*)d_in[13];

  float* out = (float*)d_out;
  float* ctx2   = out;                                      // [16][2048][512]
  float* probs2 = out + (size_t)16 * 2048 * 512;            // [16][2048][1024]
  float* ctx1   = probs2 + (size_t)16 * 2048 * 1024;        // [16][1024][512]
  float* probs1 = ctx1 + (size_t)16 * 1024 * 512;           // [16][1024][2048]

  char* ws = (char*)d_ws;
  constexpr size_t O_WQ1T = 0;
  constexpr size_t O_WK1T = O_WQ1T + (size_t)512 * 512 * 2;
  constexpr size_t O_WV1T = O_WK1T + (size_t)512 * 512 * 2;
  constexpr size_t O_WQ2T = O_WV1T + (size_t)512 * 512 * 2;
  constexpr size_t O_WK2T = O_WQ2T + (size_t)768 * 512 * 2;
  constexpr size_t O_WV2T = O_WK2T + (size_t)768 * 512 * 2;
  constexpr size_t O_B1   = O_WV2T + (size_t)768 * 512 * 2;
  constexpr size_t O_B2   = O_B1 + 4096;
  constexpr size_t O_QK1  = O_B2 + 4096;                          // [32768][1024]
  constexpr size_t O_V1T  = O_QK1 + (size_t)32768 * 1024 * 2;     // [16][512][2048]
  constexpr size_t O_QK2  = O_V1T + (size_t)16 * 512 * 2048 * 2;  // [16384][1024]
  constexpr size_t O_V2T  = O_QK2 + (size_t)16384 * 1024 * 2;     // [16][512][1024]
  constexpr size_t O_X1B  = O_V2T + (size_t)16 * 512 * 1024 * 2;  // [32768][512]
  constexpr size_t O_X2B  = O_X1B + (size_t)32768 * 512 * 2;      // [16384][768]
  constexpr size_t O_PB1  = O_X2B + (size_t)16384 * 768 * 2;      // bf16 probs1
  constexpr size_t O_PB2  = O_PB1 + (size_t)16 * 1024 * 2048 * 2; // bf16 probs2
  constexpr size_t NEED_A = O_PB2 + (size_t)16 * 2048 * 1024 * 2;
  constexpr size_t NEED_B = O_PB1;

  short* wq1t = (short*)(ws + O_WQ1T);
  short* wk1t = (short*)(ws + O_WK1T);
  short* wv1t = (short*)(ws + O_WV1T);
  short* wq2t = (short*)(ws + O_WQ2T);
  short* wk2t = (short*)(ws + O_WK2T);
  short* wv2t = (short*)(ws + O_WV2T);
  float* b1c  = (float*)(ws + O_B1);
  float* b2c  = (float*)(ws + O_B2);
  short* qk1  = (short*)(ws + O_QK1);
  short* v1t  = (short*)(ws + O_V1T);
  short* qk2  = (short*)(ws + O_QK2);
  short* v2t  = (short*)(ws + O_V2T);
  short* x1b  = (short*)(ws + O_X1B);
  short* x2b  = (short*)(ws + O_X2B);
  short* pb1  = (short*)(ws + O_PB1);
  short* pb2  = (short*)(ws + O_PB2);

  const bool tierA = ws_size >= NEED_A;
  const bool tierB = ws_size >= NEED_B;
  if (!tierB) { x1b = (short*)probs1; x2b = (short*)probs2; }

  dim3 blk256(256), blk512(512);
  dim3 blkT(32, 8);

  // ---- stage 0: one fused launch (15680 blocks) ----
  stage0<<<dim3(15680), blkT, 0, stream>>>(
      in1, in2, x1b, x2b, Wq1, Wk1, Wv1, Wq2, Wk2, Wv2,
      wq1t, wk1t, wv1t, wq2t, wk2t, wv2t,
      bq1, bk1, bq2, bk2, b1c, b2c);

  const float scale = 0.04419417382415922f;  // 1/sqrt(512)
  const short* q1p = qk1;        // lda 1024
  const short* k1p = qk1 + 512;
  const short* q2p = qk2;
  const short* k2p = qk2 + 512;

  if (tierA) {
    // ---- P1: qk1 + qk2 ----
    gemm8d<0, 1, 8, 3, 2><<<dim3(768), blk512, 0, stream>>>(
        x1b, wq1t, b1c, qk1, nullptr, 512, 512, 512, 1024, 0, 0, 0,
        4u, 128u, 512u,
        x2b, wq2t, b2c, qk2, nullptr, 768, 768, 768, 1024, 0, 0, 0,
        4u, 64u, 1.f);
    // ---- P2: v1t + v2t (MR=4) ----
    gemm8d<0, 2, 4, 3, 2><<<dim3(768), blk512, 0, stream>>>(
        wv1t, x1b, bv1, v1t, nullptr, 512, 512, 512, 2048,
        0, (long long)2048 * 512, (long long)512 * 2048,
        8u, 4u, 512u,
        wv2t, x2b, bv2, v2t, nullptr, 768, 768, 768, 1024,
        0, (long long)1024 * 768, (long long)512 * 1024,
        4u, 4u, 1.f);
    // ---- P3: scores1 + scores2 ----
    gemm8d<3, 0, 8, 3, 2><<<dim3(1024), blk512, 0, stream>>>(
        q2p, k1p, nullptr, probs1, pb1, 512, 1024, 1024, 2048,
        (long long)1024 * 1024, (long long)2048 * 1024, (long long)1024 * 2048,
        8u, 4u, 512u,
        q1p, k2p, nullptr, probs2, pb2, 512, 1024, 1024, 1024,
        (long long)2048 * 1024, (long long)1024 * 1024, (long long)2048 * 1024,
        4u, 8u, scale);
    // ---- P4: ctx1 + ctx2 (MR=4, DEPTH=2: 72KB LDS + VGPR<=128 -> 2 blk/CU) ----
    gemm8d<1, 0, 4, 2, 4><<<dim3(768), blk512, 0, stream>>>(
        pb1, v1t, nullptr, ctx1, nullptr, 2048, 2048, 2048, 512,
        (long long)1024 * 2048, (long long)512 * 2048, (long long)1024 * 512,
        2u, 8u, 256u,
        pb2, v2t, nullptr, ctx2, nullptr, 1024, 1024, 1024, 512,
        (long long)2048 * 1024, (long long)512 * 1024, (long long)2048 * 512,
        2u, 16u, 1.f);
  } else {
    gemm_bt<0, 1, 0><<<dim3(8, 256, 1), blk256, 0, stream>>>(
        x1b, wq1t, b1c, qk1, nullptr, 512, 512, 512, 1024, 0, 0, 0, 1.f);
    gemm_bt<0, 1, 0><<<dim3(8, 128, 1), blk256, 0, stream>>>(
        x2b, wq2t, b2c, qk2, nullptr, 768, 768, 768, 1024, 0, 0, 0, 1.f);
    gemm_bt<0, 2, 0><<<dim3(16, 4, 16), blk256, 0, stream>>>(
        wv1t, x1b, bv1, v1t, nullptr, 512, 512, 512, 2048,
        0, (long long)2048 * 512, (long long)512 * 2048, 1.f);
    gemm_bt<0, 2, 0><<<dim3(8, 4, 16), blk256, 0, stream>>>(
        wv2t, x2b, bv2, v2t, nullptr, 768, 768, 768, 1024,
        0, (long long)1024 * 768, (long long)512 * 1024, 1.f);
    gemm_bt<2, 0, 0><<<dim3(16, 8, 16), blk256, 0, stream>>>(
        q2p, k1p, nullptr, probs1, nullptr, 512, 1024, 1024, 2048,
        (long long)1024 * 1024, (long long)2048 * 1024, (long long)1024 * 2048, scale);
    gemm_bt<2, 0, 0><<<dim3(8, 16, 16), blk256, 0, stream>>>(
        q1p, k2p, nullptr, probs2, nullptr, 512, 1024, 1024, 1024,
        (long long)2048 * 1024, (long long)1024 * 1024, (long long)2048 * 1024, scale);
    gemm_bt<1, 0, 1><<<dim3(4, 8, 16), blk256, 0, stream>>>(
        probs1, v1t, nullptr, ctx1, nullptr, 2048, 2048, 2048, 512,
        (long long)1024 * 2048, (long long)512 * 2048, (long long)1024 * 512, 1.f);
    gemm_bt<1, 0, 1><<<dim3(4, 16, 16), blk256, 0, stream>>>(
        probs2, v2t, nullptr, ctx2, nullptr, 1024, 1024, 1024, 512,
        (long long)2048 * 1024, (long long)512 * 1024, (long long)2048 * 512, 1.f);
  }
}

// Round 14
// 428.615 us; speedup vs baseline: 1.1553x; 1.0031x over previous
//
#include <hip/hip_runtime.h>
#include <hip/hip_bf16.h>

#define DEVFN __device__ __forceinline__
#define SB __builtin_amdgcn_sched_barrier(0)

typedef __attribute__((ext_vector_type(4))) float f32x4;
typedef __attribute__((ext_vector_type(8))) short s16x8;
typedef __attribute__((ext_vector_type(2))) short s16x2;
typedef __attribute__((ext_vector_type(8))) __bf16 bf16x8;

union FragU { s16x8 s; bf16x8 b; };

DEVFN short f2bs(float x) {
  union { __hip_bfloat16 h; short s; } u;
  u.h = __float2bfloat16(x);
  return u.s;
}

DEVFN void gload16(const void* g, void* l) {
  __builtin_amdgcn_global_load_lds(
      (const __attribute__((address_space(1))) void*)g,
      (__attribute__((address_space(3))) void*)l, 16, 0, 0);
}

template <int N> DEVFN void waitcnt_vm() {
  if constexpr (N == 0) asm volatile("s_waitcnt vmcnt(0)" ::: "memory");
  else if constexpr (N == 2) asm volatile("s_waitcnt vmcnt(2)" ::: "memory");
  else if constexpr (N == 3) asm volatile("s_waitcnt vmcnt(3)" ::: "memory");
  else if constexpr (N == 4) asm volatile("s_waitcnt vmcnt(4)" ::: "memory");
  else if constexpr (N == 6) asm volatile("s_waitcnt vmcnt(6)" ::: "memory");
  else if constexpr (N == 8) asm volatile("s_waitcnt vmcnt(8)" ::: "memory");
  else static_assert(N == 0, "unsupported vmcnt");
}

// ---------------------------------------------------------------------------
// Fused stage 0 (R12-verified).
// ---------------------------------------------------------------------------
DEVFN void tr_tile(const float* __restrict__ in, short* __restrict__ out,
                   int C, int L, int l0, int c0, size_t base,
                   float (*tile)[33], int tx, int ty) {
#pragma unroll
  for (int i = ty; i < 64; i += 8)
    tile[i][tx] = in[base + (size_t)(c0 + i) * L + l0 + tx];
  __syncthreads();
#pragma unroll
  for (int i = ty; i < 32; i += 8) {
    s16x2 v;
    v[0] = f2bs(tile[2 * tx][i]);
    v[1] = f2bs(tile[2 * tx + 1][i]);
    *(s16x2*)&out[base + (size_t)(l0 + i) * C + c0 + 2 * tx] = v;
  }
}

__global__ __launch_bounds__(256) void stage0(
    const float* __restrict__ in1, const float* __restrict__ in2,
    short* x1b, short* x2b,
    const float* __restrict__ Wq1, const float* __restrict__ Wk1,
    const float* __restrict__ Wv1, const float* __restrict__ Wq2,
    const float* __restrict__ Wk2, const float* __restrict__ Wv2,
    short* wq1t, short* wk1t, short* wv1t,
    short* wq2t, short* wk2t, short* wv2t,
    const float* __restrict__ bq1, const float* __restrict__ bk1,
    const float* __restrict__ bq2, const float* __restrict__ bk2,
    float* b1c, float* b2c) {
  __shared__ float tile[64][33];
  const int tx = threadIdx.x, ty = threadIdx.y;
  const unsigned b = blockIdx.x;
  if (b < 8192u) {
    const int x = b & 63, y = (b >> 6) & 7, z = b >> 9;
    tr_tile(in1, x1b, 512, 2048, x * 32, y * 64,
            (size_t)z * 512 * 2048, tile, tx, ty);
    return;
  }
  if (b < 14336u) {
    const unsigned bb = b - 8192u;
    const int x = bb & 31, y = (bb >> 5) % 12, z = bb / 384;
    tr_tile(in2, x2b, 768, 1024, x * 32, y * 64,
            (size_t)z * 768 * 1024, tile, tx, ty);
    return;
  }
  const unsigned bb = b - 14336u;
  const int x = bb & 15, y = (bb >> 4) % 12, z = bb / 192;
  if (z == 6) {
    if (y != 0 || x >= 8) return;
    const int tid = ty * 32 + tx;
    const int i = (x & 3) * 256 + tid;
    const float* s = (x < 4) ? ((i < 512) ? bq1 : bk1)
                             : ((i < 512) ? bq2 : bk2);
    float* d = (x < 4) ? b1c : b2c;
    d[i] = s[i & 511];
    return;
  }
  const float* W; short* O; int C;
  switch (z) {
    case 0: W = Wq1; O = wq1t; C = 512; break;
    case 1: W = Wk1; O = wk1t; C = 512; break;
    case 2: W = Wv1; O = wv1t; C = 512; break;
    case 3: W = Wq2; O = wq2t; C = 768; break;
    case 4: W = Wk2; O = wk2t; C = 768; break;
    default: W = Wv2; O = wv2t; C = 768; break;
  }
  if (y * 64 >= C) return;
  tr_tile(W, O, C, 512, x * 32, y * 64, 0, tile, tx, ty);
}

// ---------------------------------------------------------------------------
// Dual-GEMM launch: deep-pipelined 256xBN (BM = MR*32).
// MR=8: 4-phase quadrant interleave per K-step (Q00: stageA + fa0-3/fb0-1 +
// 8 MFMA; Q01: fb2-3 + 8; Q10: stageB + fa4-7 + 8; Q11: 8 reg-only).
// MR=4: proven 2-phase path. Staging/wait accounting identical to R12
// (all of stage(t+DEPTH) issued within iter t; counted end-of-iter vmcnt).
// DEPTH=3: 4 bufs. DEPTH=2: 3 bufs (MR=4: 72KB + MINW=4 -> 2 blocks/CU).
// OUTMODE: 0=bf16, 1=f32(nt), 2=sigmoid f32(nt), 3=sigmoid f32(nt)+bf16 D
// BIASMODE: 0 none, 1 per-n, 2 per-m.  Requires NT = K/32 >= DEPTH.
// ---------------------------------------------------------------------------
template <int OUTMODE, int BIASMODE, int MR, int DEPTH, int MINW>
__global__ __launch_bounds__(512, MINW) void gemm8d(
    const short* __restrict__ A0, const short* __restrict__ B0,
    const float* __restrict__ bias0, void* __restrict__ C0, short* __restrict__ D0,
    int K0, int lda0, int ldb0, int ldc0,
    long long sA0, long long sB0, long long sC0,
    unsigned gx0, unsigned gy0, unsigned nb0,
    const short* __restrict__ A1, const short* __restrict__ B1,
    const float* __restrict__ bias1, void* __restrict__ C1, short* __restrict__ D1,
    int K1, int lda1, int ldb1, int ldc1,
    long long sA1, long long sB1, long long sC1,
    unsigned gx1, unsigned gy1, float scale) {
  constexpr int BM = MR * 32;
  constexpr int BN = 256;
  constexpr int LA = BM / 128;
  constexpr int LB = BN / 128;
  constexpr int LPT = LA + LB;
  constexpr int ABYTES = BM * 64;
  constexpr int BUFB = (BM + BN) * 64;
  constexpr int NBUF = DEPTH + 1;
  constexpr int MH = MR / 2;
  __shared__ __align__(16) char smem[NBUF * BUFB];
  const int tid = threadIdx.x;
  const int lane = tid & 63, wid = tid >> 6;
  const int wm = wid >> 2, wn = wid & 3;

  const unsigned h = blockIdx.x;
  const bool sec = h >= nb0;
  const unsigned hh = sec ? h - nb0 : h;
  const unsigned nb = sec ? gridDim.x - nb0 : nb0;
  const unsigned gx = sec ? gx1 : gx0;
  const unsigned gy = sec ? gy1 : gy0;
  const short* Ap = sec ? A1 : A0;
  const short* Btp = sec ? B1 : B0;
  const float* bias = sec ? bias1 : bias0;
  void* Cptr = sec ? C1 : C0;
  short* C2p = sec ? D1 : D0;
  const int K = sec ? K1 : K0;
  const int lda = sec ? lda1 : lda0;
  const int ldb = sec ? ldb1 : ldb0;
  const int ldc = sec ? ldc1 : ldc0;
  const long long sA = sec ? sA1 : sA0;
  const long long sB = sec ? sB1 : sB0;
  const long long sC = sec ? sC1 : sC0;

  unsigned l = ((nb & 7u) == 0u) ? (hh & 7u) * (nb >> 3) + (hh >> 3) : hh;
  const unsigned bx = l % gx;
  const unsigned rem = l / gx;
  const unsigned by = rem % gy;
  const unsigned bz = rem / gy;

  const int zb = bz;
  const int m0 = by * BM, n0 = bx * BN;
  const char* Ab = (const char*)(Ap + (size_t)zb * sA);
  const char* Bb = (const char*)(Btp + (size_t)zb * sB);
  const size_t lda2 = (size_t)lda * 2, ldb2 = (size_t)ldb * 2;

  int s_r[2], s_cb[2];
#pragma unroll
  for (int j = 0; j < 2; ++j) {
    const int d = j * 8192 + tid * 16;
    const int line = d >> 7;
    s_r[j] = line * 2 + ((d >> 6) & 1);
    s_cb[j] = (d & 63) ^ ((line & 3) << 4);
  }

  f32x4 acc[MR][4] = {};
  const int frow = lane & 15, fkg = lane >> 4;

  int ra[MR], rb[4];
#pragma unroll
  for (int mf = 0; mf < MR; ++mf) {
    const int R = wm * (MR * 16) + mf * 16 + frow;
    ra[mf] = (R >> 1) * 128 + (R & 1) * 64 + ((fkg * 16) ^ (((R >> 1) & 3) << 4));
  }
#pragma unroll
  for (int nf = 0; nf < 4; ++nf) {
    const int R = wn * 64 + nf * 16 + frow;
    rb[nf] = (R >> 1) * 128 + (R & 1) * 64 + ((fkg * 16) ^ (((R >> 1) & 3) << 4));
  }

  const int NT = K >> 5;

#define STAGE_A(t)                                                       \
  {                                                                      \
    char* base_ = smem + ((t) % NBUF) * BUFB;                            \
    const size_t kb_ = (size_t)(t) * 64;                                 \
    _Pragma("unroll")                                                    \
    for (int j = 0; j < LA; ++j)                                         \
      gload16(Ab + (size_t)(m0 + s_r[j]) * lda2 + kb_ + s_cb[j],         \
              base_ + j * 8192 + tid * 16);                              \
  }
#define STAGE_B(t)                                                       \
  {                                                                      \
    char* base_ = smem + ((t) % NBUF) * BUFB + ABYTES;                   \
    const size_t kb_ = (size_t)(t) * 64;                                 \
    _Pragma("unroll")                                                    \
    for (int j = 0; j < LB; ++j)                                         \
      gload16(Bb + (size_t)(n0 + s_r[j]) * ldb2 + kb_ + s_cb[j],         \
              base_ + j * 8192 + tid * 16);                              \
  }

  STAGE_A(0); STAGE_B(0);
  STAGE_A(1); STAGE_B(1);
  if constexpr (DEPTH == 3) { STAGE_A(2); STAGE_B(2); }
  waitcnt_vm<(DEPTH - 1) * LPT>();
  SB; __builtin_amdgcn_s_barrier(); SB;

  for (int t = 0; t < NT; ++t) {
    const char* la = smem + (t % NBUF) * BUFB;
    const char* lb = la + ABYTES;
    FragU fa[MR], fb[4];
    if constexpr (MR == 8) {
      // ---- Q00: stage A(t+D) | read fa[0..4), fb[0..2) | MFMA mf<4,nf<2 ----
      if (t + DEPTH < NT) STAGE_A(t + DEPTH);
#pragma unroll
      for (int mf = 0; mf < 4; ++mf) fa[mf].s = *(const s16x8*)(la + ra[mf]);
#pragma unroll
      for (int nf = 0; nf < 2; ++nf) fb[nf].s = *(const s16x8*)(lb + rb[nf]);
      __builtin_amdgcn_s_barrier();
      asm volatile("s_waitcnt lgkmcnt(0)" ::: "memory");
      SB;
      __builtin_amdgcn_s_setprio(1);
#pragma unroll
      for (int mf = 0; mf < 4; ++mf)
#pragma unroll
        for (int nf = 0; nf < 2; ++nf)
          acc[mf][nf] = __builtin_amdgcn_mfma_f32_16x16x32_bf16(
              fa[mf].b, fb[nf].b, acc[mf][nf], 0, 0, 0);
      __builtin_amdgcn_s_setprio(0);
      __builtin_amdgcn_s_barrier();
      // ---- Q01: read fb[2..4) | MFMA mf<4,nf>=2 ----
#pragma unroll
      for (int nf = 2; nf < 4; ++nf) fb[nf].s = *(const s16x8*)(lb + rb[nf]);
      __builtin_amdgcn_s_barrier();
      asm volatile("s_waitcnt lgkmcnt(0)" ::: "memory");
      SB;
      __builtin_amdgcn_s_setprio(1);
#pragma unroll
      for (int mf = 0; mf < 4; ++mf)
#pragma unroll
        for (int nf = 2; nf < 4; ++nf)
          acc[mf][nf] = __builtin_amdgcn_mfma_f32_16x16x32_bf16(
              fa[mf].b, fb[nf].b, acc[mf][nf], 0, 0, 0);
      __builtin_amdgcn_s_setprio(0);
      __builtin_amdgcn_s_barrier();
      // ---- Q10: stage B(t+D) | read fa[4..8) | MFMA mf>=4,nf<2 ----
      if (t + DEPTH < NT) STAGE_B(t + DEPTH);
#pragma unroll
      for (int mf = 4; mf < 8; ++mf) fa[mf].s = *(const s16x8*)(la + ra[mf]);
      __builtin_amdgcn_s_barrier();
      asm volatile("s_waitcnt lgkmcnt(0)" ::: "memory");
      SB;
      __builtin_amdgcn_s_setprio(1);
#pragma unroll
      for (int mf = 4; mf < 8; ++mf)
#pragma unroll
        for (int nf = 0; nf < 2; ++nf)
          acc[mf][nf] = __builtin_amdgcn_mfma_f32_16x16x32_bf16(
              fa[mf].b, fb[nf].b, acc[mf][nf], 0, 0, 0);
      __builtin_amdgcn_s_setprio(0);
      __builtin_amdgcn_s_barrier();
      // ---- Q11: MFMA mf>=4,nf>=2 (reg-only) ----
      __builtin_amdgcn_s_setprio(1);
#pragma unroll
      for (int mf = 4; mf < 8; ++mf)
#pragma unroll
        for (int nf = 2; nf < 4; ++nf)
          acc[mf][nf] = __builtin_amdgcn_mfma_f32_16x16x32_bf16(
              fa[mf].b, fb[nf].b, acc[mf][nf], 0, 0, 0);
      __builtin_amdgcn_s_setprio(0);
    } else {
      // ---- 2-phase path (MR=4, proven) ----
      if (t + DEPTH < NT) STAGE_A(t + DEPTH);
#pragma unroll
      for (int mf = 0; mf < MH; ++mf) fa[mf].s = *(const s16x8*)(la + ra[mf]);
#pragma unroll
      for (int nf = 0; nf < 4; ++nf) fb[nf].s = *(const s16x8*)(lb + rb[nf]);
      __builtin_amdgcn_s_barrier();
      asm volatile("s_waitcnt lgkmcnt(0)" ::: "memory");
      SB;
      __builtin_amdgcn_s_setprio(1);
#pragma unroll
      for (int mf = 0; mf < MH; ++mf)
#pragma unroll
        for (int nf = 0; nf < 4; ++nf)
          acc[mf][nf] = __builtin_amdgcn_mfma_f32_16x16x32_bf16(
              fa[mf].b, fb[nf].b, acc[mf][nf], 0, 0, 0);
      __builtin_amdgcn_s_setprio(0);
      __builtin_amdgcn_s_barrier();
      if (t + DEPTH < NT) STAGE_B(t + DEPTH);
#pragma unroll
      for (int mf = MH; mf < MR; ++mf) fa[mf].s = *(const s16x8*)(la + ra[mf]);
      __builtin_amdgcn_s_barrier();
      asm volatile("s_waitcnt lgkmcnt(0)" ::: "memory");
      SB;
      __builtin_amdgcn_s_setprio(1);
#pragma unroll
      for (int mf = MH; mf < MR; ++mf)
#pragma unroll
        for (int nf = 0; nf < 4; ++nf)
          acc[mf][nf] = __builtin_amdgcn_mfma_f32_16x16x32_bf16(
              fa[mf].b, fb[nf].b, acc[mf][nf], 0, 0, 0);
      __builtin_amdgcn_s_setprio(0);
    }
    // ---- end-of-iter wait (unchanged accounting) ----
    if constexpr (DEPTH == 3) {
      if (t + 3 < NT) {
        waitcnt_vm<2 * LPT>();
      } else if (t + 2 < NT) {
        waitcnt_vm<LPT>();
      } else if (t + 1 < NT) {
        waitcnt_vm<0>();
      } else {
        break;
      }
    } else {
      if (t + 2 < NT) {
        waitcnt_vm<LPT>();
      } else if (t + 1 < NT) {
        waitcnt_vm<0>();
      } else {
        break;
      }
    }
    SB; __builtin_amdgcn_s_barrier(); SB;
  }
#undef STAGE_A
#undef STAGE_B

  const int rbase = (lane >> 4) * 4, cbase = lane & 15;
#pragma unroll
  for (int mf = 0; mf < MR; ++mf) {
#pragma unroll
    for (int nf = 0; nf < 4; ++nf) {
      const int gcol = n0 + wn * 64 + nf * 16 + cbase;
      float bn = (BIASMODE == 1) ? bias[gcol] : 0.f;
#pragma unroll
      for (int r = 0; r < 4; ++r) {
        const int grow = m0 + wm * (MR * 16) + mf * 16 + rbase + r;
        const size_t idx = (size_t)zb * sC + (size_t)grow * ldc + gcol;
        float v = acc[mf][nf][r];
        if constexpr (BIASMODE == 2) v += bias[grow]; else v += bn;
        if constexpr (OUTMODE == 0) {
          ((short*)Cptr)[idx] = f2bs(v);
        } else if constexpr (OUTMODE == 1) {
          __builtin_nontemporal_store(v, &((float*)Cptr)[idx]);
        } else if constexpr (OUTMODE == 2) {
          float p = 1.0f / (1.0f + __expf(-v * scale));
          __builtin_nontemporal_store(p, &((float*)Cptr)[idx]);
        } else {
          float p = 1.0f / (1.0f + __expf(-v * scale));
          __builtin_nontemporal_store(p, &((float*)Cptr)[idx]);
          C2p[idx] = f2bs(p);
        }
      }
    }
  }
}

// ---------------------------------------------------------------------------
// Fallback (tierB only): gload-staged 128x128 BK=64 GEMM, AF32 supported.
// ---------------------------------------------------------------------------
template <int OUTMODE, int BIASMODE, int AF32>
__global__ __launch_bounds__(256) void gemm_bt(
    const void* __restrict__ Aptr, const short* __restrict__ Btp,
    const float* __restrict__ bias, void* __restrict__ Cptr,
    short* __restrict__ C2p,
    int K, int lda, int ldb, int ldc,
    long long sA, long long sB, long long sC, float scale) {
  __shared__ __align__(16) short lsA[128 * 64];
  __shared__ __align__(16) short lsB[128 * 64];
  const int tid = threadIdx.x;
  const int lane = tid & 63, wid = tid >> 6;
  const int zb = blockIdx.z;
  const int m0 = blockIdx.y * 128, n0 = blockIdx.x * 128;
  const short* Ab = AF32 ? nullptr : (const short*)Aptr + (size_t)zb * sA;
  const float* Af = AF32 ? (const float*)Aptr + (size_t)zb * sA : nullptr;
  const short* Bt = Btp + (size_t)zb * sB;

  f32x4 acc[4][4] = {};
  const int woffM = (wid >> 1) * 64, woffN = (wid & 1) * 64;
  const int frow = lane & 15, fkg = lane >> 4;

  for (int k0 = 0; k0 < K; k0 += 64) {
    if (k0) __syncthreads();
    if constexpr (!AF32) {
#pragma unroll
      for (int i = 0; i < 4; ++i) {
        const int f = i * 4096 + tid * 16;
        const int row = f >> 7, colb = f & 127;
        gload16((const char*)Ab + ((size_t)(m0 + row) * lda + k0) * 2 + colb,
                (char*)lsA + f);
      }
    } else {
#pragma unroll
      for (int i = 0; i < 8; ++i) {
        int f = tid + i * 256;
        int row = f >> 4, c4 = f & 15;
        f32x4 v = *(const f32x4*)&Af[(size_t)(m0 + row) * lda + k0 + c4 * 4];
        union { short s[4]; unsigned long long q; } cv;
#pragma unroll
        for (int j = 0; j < 4; ++j) cv.s[j] = f2bs(v[j]);
        *(unsigned long long*)&lsA[row * 64 + c4 * 4] = cv.q;
      }
    }
#pragma unroll
    for (int i = 0; i < 4; ++i) {
      const int f = i * 4096 + tid * 16;
      const int row = f >> 7, colb = f & 127;
      gload16((const char*)Bt + ((size_t)(n0 + row) * ldb + k0) * 2 + colb,
              (char*)lsB + f);
    }
    __syncthreads();
#pragma unroll
    for (int kk = 0; kk < 2; ++kk) {
      const int kb = kk * 32 + fkg * 8;
      FragU fa[4], fb[4];
#pragma unroll
      for (int mf = 0; mf < 4; ++mf)
        fa[mf].s = *(const s16x8*)&lsA[(woffM + mf * 16 + frow) * 64 + kb];
#pragma unroll
      for (int nf = 0; nf < 4; ++nf)
        fb[nf].s = *(const s16x8*)&lsB[(woffN + nf * 16 + frow) * 64 + kb];
#pragma unroll
      for (int mf = 0; mf < 4; ++mf)
#pragma unroll
        for (int nf = 0; nf < 4; ++nf)
          acc[mf][nf] = __builtin_amdgcn_mfma_f32_16x16x32_bf16(
              fa[mf].b, fb[nf].b, acc[mf][nf], 0, 0, 0);
    }
  }

  const int rbase = (lane >> 4) * 4, cbase = lane & 15;
#pragma unroll
  for (int mf = 0; mf < 4; ++mf) {
#pragma unroll
    for (int nf = 0; nf < 4; ++nf) {
      const int gcol = n0 + woffN + nf * 16 + cbase;
      float bn = (BIASMODE == 1) ? bias[gcol] : 0.f;
#pragma unroll
      for (int r = 0; r < 4; ++r) {
        const int grow = m0 + woffM + mf * 16 + rbase + r;
        const size_t idx = (size_t)zb * sC + (size_t)grow * ldc + gcol;
        float v = acc[mf][nf][r];
        if constexpr (BIASMODE == 2) v += bias[grow]; else v += bn;
        if constexpr (OUTMODE == 0) {
          ((short*)Cptr)[idx] = f2bs(v);
        } else if constexpr (OUTMODE == 1) {
          ((float*)Cptr)[idx] = v;
        } else if constexpr (OUTMODE == 2) {
          ((float*)Cptr)[idx] = 1.0f / (1.0f + __expf(-v * scale));
        } else {
          float p = 1.0f / (1.0f + __expf(-v * scale));
          ((float*)Cptr)[idx] = p;
          C2p[idx] = f2bs(p);
        }
      }
    }
  }
}

extern "C" void kernel_launch(void* const* d_in, const int* in_sizes, int n_in,
                              void* d_out, int out_size, void* d_ws, size_t ws_size,
                              hipStream_t stream) {
  const float* in1 = (const float*)d_in[0];   // [16][512][2048]
  const float* in2 = (const float*)d_in[1];   // [16][768][1024]
  const float* Wq1 = (const float*)d_in[2];  const float* bq1 = (const float*)d_in[3];
  const float* Wk1 = (const float*)d_in[4];  const float* bk1 = (const float*)d_in[5];
  const float* Wv1 = (const float*)d_in[6];  const float* bv1 = (const float*)d_in[7];
  const float* Wq2 = (const float*)d_in[8];  const float* bq2 = (const float*)d_in[9];
  const float* Wk2 = (const float*)d_in[10]; const float* bk2 = (const float*)d_in[11];
  const float* Wv2 = (const float*)d_in[12]; const float* bv2 = (const float*)d_in[13];

  float* out = (float*)d_out;
  float* ctx2   = out;                                      // [16][2048][512]
  float* probs2 = out + (size_t)16 * 2048 * 512;            // [16][2048][1024]
  float* ctx1   = probs2 + (size_t)16 * 2048 * 1024;        // [16][1024][512]
  float* probs1 = ctx1 + (size_t)16 * 1024 * 512;           // [16][1024][2048]

  char* ws = (char*)d_ws;
  constexpr size_t O_WQ1T = 0;
  constexpr size_t O_WK1T = O_WQ1T + (size_t)512 * 512 * 2;
  constexpr size_t O_WV1T = O_WK1T + (size_t)512 * 512 * 2;
  constexpr size_t O_WQ2T = O_WV1T + (size_t)512 * 512 * 2;
  constexpr size_t O_WK2T = O_WQ2T + (size_t)768 * 512 * 2;
  constexpr size_t O_WV2T = O_WK2T + (size_t)768 * 512 * 2;
  constexpr size_t O_B1   = O_WV2T + (size_t)768 * 512 * 2;
  constexpr size_t O_B2   = O_B1 + 4096;
  constexpr size_t O_QK1  = O_B2 + 4096;                          // [32768][1024]
  constexpr size_t O_V1T  = O_QK1 + (size_t)32768 * 1024 * 2;     // [16][512][2048]
  constexpr size_t O_QK2  = O_V1T + (size_t)16 * 512 * 2048 * 2;  // [16384][1024]
  constexpr size_t O_V2T  = O_QK2 + (size_t)16384 * 1024 * 2;     // [16][512][1024]
  constexpr size_t O_X1B  = O_V2T + (size_t)16 * 512 * 1024 * 2;  // [32768][512]
  constexpr size_t O_X2B  = O_X1B + (size_t)32768 * 512 * 2;      // [16384][768]
  constexpr size_t O_PB1  = O_X2B + (size_t)16384 * 768 * 2;      // bf16 probs1
  constexpr size_t O_PB2  = O_PB1 + (size_t)16 * 1024 * 2048 * 2; // bf16 probs2
  constexpr size_t NEED_A = O_PB2 + (size_t)16 * 2048 * 1024 * 2;
  constexpr size_t NEED_B = O_PB1;

  short* wq1t = (short*)(ws + O_WQ1T);
  short* wk1t = (short*)(ws + O_WK1T);
  short* wv1t = (short*)(ws + O_WV1T);
  short* wq2t = (short*)(ws + O_WQ2T);
  short* wk2t = (short*)(ws + O_WK2T);
  short* wv2t = (short*)(ws + O_WV2T);
  float* b1c  = (float*)(ws + O_B1);
  float* b2c  = (float*)(ws + O_B2);
  short* qk1  = (short*)(ws + O_QK1);
  short* v1t  = (short*)(ws + O_V1T);
  short* qk2  = (short*)(ws + O_QK2);
  short* v2t  = (short*)(ws + O_V2T);
  short* x1b  = (short*)(ws + O_X1B);
  short* x2b  = (short*)(ws + O_X2B);
  short* pb1  = (short*)(ws + O_PB1);
  short* pb2  = (short*)(ws + O_PB2);

  const bool tierA = ws_size >= NEED_A;
  const bool tierB = ws_size >= NEED_B;
  if (!tierB) { x1b = (short*)probs1; x2b = (short*)probs2; }

  dim3 blk256(256), blk512(512);
  dim3 blkT(32, 8);

  // ---- stage 0: one fused launch (15680 blocks) ----
  stage0<<<dim3(15680), blkT, 0, stream>>>(
      in1, in2, x1b, x2b, Wq1, Wk1, Wv1, Wq2, Wk2, Wv2,
      wq1t, wk1t, wv1t, wq2t, wk2t, wv2t,
      bq1, bk1, bq2, bk2, b1c, b2c);

  const float scale = 0.04419417382415922f;  // 1/sqrt(512)
  const short* q1p = qk1;        // lda 1024
  const short* k1p = qk1 + 512;
  const short* q2p = qk2;
  const short* k2p = qk2 + 512;

  if (tierA) {
    // ---- P1: qk1 + qk2 (MR=8, 4-phase) ----
    gemm8d<0, 1, 8, 3, 2><<<dim3(768), blk512, 0, stream>>>(
        x1b, wq1t, b1c, qk1, nullptr, 512, 512, 512, 1024, 0, 0, 0,
        4u, 128u, 512u,
        x2b, wq2t, b2c, qk2, nullptr, 768, 768, 768, 1024, 0, 0, 0,
        4u, 64u, 1.f);
    // ---- P2: v1t + v2t (MR=4, 2-phase) ----
    gemm8d<0, 2, 4, 3, 2><<<dim3(768), blk512, 0, stream>>>(
        wv1t, x1b, bv1, v1t, nullptr, 512, 512, 512, 2048,
        0, (long long)2048 * 512, (long long)512 * 2048,
        8u, 4u, 512u,
        wv2t, x2b, bv2, v2t, nullptr, 768, 768, 768, 1024,
        0, (long long)1024 * 768, (long long)512 * 1024,
        4u, 4u, 1.f);
    // ---- P3: scores1 + scores2 (MR=8, 4-phase) ----
    gemm8d<3, 0, 8, 3, 2><<<dim3(1024), blk512, 0, stream>>>(
        q2p, k1p, nullptr, probs1, pb1, 512, 1024, 1024, 2048,
        (long long)1024 * 1024, (long long)2048 * 1024, (long long)1024 * 2048,
        8u, 4u, 512u,
        q1p, k2p, nullptr, probs2, pb2, 512, 1024, 1024, 1024,
        (long long)2048 * 1024, (long long)1024 * 1024, (long long)2048 * 1024,
        4u, 8u, scale);
    // ---- P4: ctx1 + ctx2 (MR=4, DEPTH=2, 2 blocks/CU) ----
    gemm8d<1, 0, 4, 2, 4><<<dim3(768), blk512, 0, stream>>>(
        pb1, v1t, nullptr, ctx1, nullptr, 2048, 2048, 2048, 512,
        (long long)1024 * 2048, (long long)512 * 2048, (long long)1024 * 512,
        2u, 8u, 256u,
        pb2, v2t, nullptr, ctx2, nullptr, 1024, 1024, 1024, 512,
        (long long)2048 * 1024, (long long)512 * 1024, (long long)2048 * 512,
        2u, 16u, 1.f);
  } else {
    gemm_bt<0, 1, 0><<<dim3(8, 256, 1), blk256, 0, stream>>>(
        x1b, wq1t, b1c, qk1, nullptr, 512, 512, 512, 1024, 0, 0, 0, 1.f);
    gemm_bt<0, 1, 0><<<dim3(8, 128, 1), blk256, 0, stream>>>(
        x2b, wq2t, b2c, qk2, nullptr, 768, 768, 768, 1024, 0, 0, 0, 1.f);
    gemm_bt<0, 2, 0><<<dim3(16, 4, 16), blk256, 0, stream>>>(
        wv1t, x1b, bv1, v1t, nullptr, 512, 512, 512, 2048,
        0, (long long)2048 * 512, (long long)512 * 2048, 1.f);
    gemm_bt<0, 2, 0><<<dim3(8, 4, 16), blk256, 0, stream>>>(
        wv2t, x2b, bv2, v2t, nullptr, 768, 768, 768, 1024,
        0, (long long)1024 * 768, (long long)512 * 1024, 1.f);
    gemm_bt<2, 0, 0><<<dim3(16, 8, 16), blk256, 0, stream>>>(
        q2p, k1p, nullptr, probs1, nullptr, 512, 1024, 1024, 2048,
        (long long)1024 * 1024, (long long)2048 * 1024, (long long)1024 * 2048, scale);
    gemm_bt<2, 0, 0><<<dim3(8, 16, 16), blk256, 0, stream>>>(
        q1p, k2p, nullptr, probs2, nullptr, 512, 1024, 1024, 1024,
        (long long)2048 * 1024, (long long)1024 * 1024, (long long)2048 * 1024, scale);
    gemm_bt<1, 0, 1><<<dim3(4, 8, 16), blk256, 0, stream>>>(
        probs1, v1t, nullptr, ctx1, nullptr, 2048, 2048, 2048, 512,
        (long long)1024 * 2048, (long long)512 * 2048, (long long)1024 * 512, 1.f);
    gemm_bt<1, 0, 1><<<dim3(4, 16, 16), blk256, 0, stream>>>(
        probs2, v2t, nullptr, ctx2, nullptr, 1024, 1024, 1024, 512,
        (long long)2048 * 1024, (long long)512 * 1024, (long long)2048 * 512, 1.f);
  }
}